// Round 10
// baseline (489.653 us; speedup 1.0000x reference)
//
#include <hip/hip_runtime.h>
#include <hip/hip_bf16.h>
#include <hip/hip_fp16.h>

#define D 50
#define PADH 64                     // fp16 row stride: 128 B = 2 aligned 64B lines
#define GLAM 0.05555555555555555f   // gamma * lambda = (1/(2*0.9)) * 0.1
#define SCAN_B 1024
#define MASK44 ((1ULL << 44) - 1)
#define FIXS 16777216.0f            // 2^24 fixed-point scale
#define INV_FIXS (1.0f / 16777216.0f)
#define BSHIFT 14                   // src bucket = s >> 14 (16384 nodes = 2MB fp16)

typedef unsigned long long u64;

// ---- init: pkdeg zeros (self-loop added in k_post); odeg = 1.0 ----
__global__ void k_init(u64* __restrict__ pkdeg, float* __restrict__ odeg, int n, int nnb) {
    int i = blockIdx.x * blockDim.x + threadIdx.x;
    if (i < nnb) pkdeg[i] = 0ULL;
    if (i < n) odeg[i] = 1.0f;
}

// ---- weighted degrees + (dst,src-bucket) histogram; atomic return = rank ----
__global__ void k_deg_hist(const float* __restrict__ ew, const int* __restrict__ src,
                           const int* __restrict__ dst, u64* __restrict__ pkdeg,
                           float* __restrict__ odeg, int* __restrict__ rank,
                           int e, int nb) {
    int i = blockIdx.x * blockDim.x + threadIdx.x;
    if (i < e) {
        float w = __builtin_nontemporal_load(ew + i);
        int s = __builtin_nontemporal_load(src + i);
        int t = __builtin_nontemporal_load(dst + i);
        u64 pk = (1ULL << 44) + (u64)(w * FIXS + 0.5f);
        u64 old = atomicAdd(&pkdeg[t * nb + (s >> BSHIFT)], pk);
        rank[i] = (int)(old >> 44);
        atomicAdd(&odeg[s], w);
    }
}

// ---- pad feat (stride 50 fp32) -> xp (stride 64 fp16, zeros in pad) ----
__global__ void k_pad(const float* __restrict__ feat, __half* __restrict__ xp, int n) {
    int i = blockIdx.x * blockDim.x + threadIdx.x;
    if (i < n * PADH) {
        int node = i >> 6, col = i & 63;
        xp[i] = (col < D) ? __float2half_rn(feat[node * D + col]) : __half(0.0f);
    }
}

// ---- per node: sum bucket weights (+1 self), cnt per bucket; rsqrt ----
__global__ void k_post(const u64* __restrict__ pkdeg, float* __restrict__ odeg,
                       float* __restrict__ isi, int* __restrict__ cnt,
                       int n, int nb) {
    int i = blockIdx.x * blockDim.x + threadIdx.x;
    if (i < n) {
        float wsum = 1.0f;                    // self-loop weight
        for (int b = 0; b < nb; ++b) {
            u64 p = pkdeg[i * nb + b];
            cnt[i * nb + b] = (int)(p >> 44);
            wsum += (float)(p & MASK44) * INV_FIXS;
        }
        isi[i] = rsqrtf(wsum);
        odeg[i] = rsqrtf(odeg[i]);            // becomes iso
    }
}

// ---- exclusive scan of cnt -> rowptr (over n*nb entries) ----
__global__ void k_scan1(const int* __restrict__ cnt, int* __restrict__ rowptr,
                        int* __restrict__ bsum, int n) {
    __shared__ int s[SCAN_B];
    int i = blockIdx.x * SCAN_B + threadIdx.x;
    int v = (i < n) ? cnt[i] : 0;
    s[threadIdx.x] = v; __syncthreads();
    for (int off = 1; off < SCAN_B; off <<= 1) {
        int t = (threadIdx.x >= (unsigned)off) ? s[threadIdx.x - off] : 0;
        __syncthreads();
        s[threadIdx.x] += t; __syncthreads();
    }
    if (i < n) rowptr[i] = s[threadIdx.x] - v;          // exclusive
    if (threadIdx.x == SCAN_B - 1) bsum[blockIdx.x] = s[threadIdx.x];
}

__global__ void k_scan2(int* __restrict__ bsum, int nb) {
    __shared__ int s[SCAN_B];
    int v = (threadIdx.x < (unsigned)nb) ? bsum[threadIdx.x] : 0;
    s[threadIdx.x] = v; __syncthreads();
    for (int off = 1; off < SCAN_B; off <<= 1) {
        int t = (threadIdx.x >= (unsigned)off) ? s[threadIdx.x - off] : 0;
        __syncthreads();
        s[threadIdx.x] += t; __syncthreads();
    }
    if (threadIdx.x < (unsigned)nb) bsum[threadIdx.x] = s[threadIdx.x] - v;  // exclusive
}

__global__ void k_scan3(int* __restrict__ rowptr, const int* __restrict__ bsum, int n) {
    int i = blockIdx.x * SCAN_B + threadIdx.x;
    if (i < n) rowptr[i] += bsum[blockIdx.x];
}

// ---- scatter edges into bucketed dst-CSR: NO atomics ----
__global__ void k_scatter(const float* __restrict__ ew, const int* __restrict__ src,
                          const int* __restrict__ dst, const float* __restrict__ iso,
                          const float* __restrict__ isi, const int* __restrict__ rowptr,
                          const int* __restrict__ rank, u64* __restrict__ pe,
                          int e, int nb) {
    int i = blockIdx.x * blockDim.x + threadIdx.x;
    if (i < e) {
        float w = __builtin_nontemporal_load(ew + i);
        int s = __builtin_nontemporal_load(src + i);
        int t = __builtin_nontemporal_load(dst + i);
        int pos = rowptr[t * nb + (s >> BSHIFT)] + __builtin_nontemporal_load(rank + i);
        float wv = w * iso[s] * isi[t];
        pe[pos] = (u64)(unsigned)s | ((u64)__float_as_uint(wv) << 32);
    }
}

// ---- fused iteration: 8 edge-slots x 8 lanes x 16B gathers + prox (R8 form) ----
__global__ void k_iter(const int* __restrict__ rowptr, const u64* __restrict__ pe,
                       const __half* __restrict__ xin, const float* __restrict__ feat,
                       const float* __restrict__ iso, const float* __restrict__ isi,
                       __half* __restrict__ hout, float* __restrict__ fout,
                       int n, int nb, int e, int final_iter) {
    int lane = threadIdx.x & 63;
    int node = blockIdx.x * (blockDim.x >> 6) + (threadIdx.x >> 6);
    if (node >= n) return;

    int slot  = lane >> 3;           // edge slot 0..7
    int chunk = lane & 7;            // 8-feature chunk 0..7

    float a0 = 0.f, a1 = 0.f, a2 = 0.f, a3 = 0.f;
    float a4 = 0.f, a5 = 0.f, a6 = 0.f, a7 = 0.f;

    int beg = rowptr[node * nb];
    int end = (node == n - 1) ? e : rowptr[(node + 1) * nb];
    int m = end - beg;

    for (int j0 = 0; j0 < m; j0 += 64) {
        int mm = m - j0; if (mm > 64) mm = 64;
        int c = 0; float ww = 0.0f;
        if (lane < mm) {
            u64 p = pe[beg + j0 + lane];
            c  = (int)(unsigned)(p & 0xffffffffULL);
            ww = __uint_as_float((unsigned)(p >> 32));
        }
        for (int jj = 0; jj < mm; jj += 8) {
            int idx = jj + slot;                 // < 64 always
            int   s = __shfl(c,  idx, 64);
            float w = __shfl(ww, idx, 64);
            if (w != 0.0f) {                     // skips junk tail slots too
                uint4 u = *(const uint4*)(xin + ((size_t)s << 6) + (chunk << 3));
                const __half2* hp = (const __half2*)&u;
                float2 f0 = __half22float2(hp[0]);
                float2 f1 = __half22float2(hp[1]);
                float2 f2 = __half22float2(hp[2]);
                float2 f3 = __half22float2(hp[3]);
                a0 = fmaf(w, f0.x, a0); a1 = fmaf(w, f0.y, a1);
                a2 = fmaf(w, f1.x, a2); a3 = fmaf(w, f1.y, a3);
                a4 = fmaf(w, f2.x, a4); a5 = fmaf(w, f2.y, a5);
                a6 = fmaf(w, f3.x, a6); a7 = fmaf(w, f3.y, a7);
            }
        }
    }

    // combine across the 8 slots (fixed chunk): xor masks 8,16,32
    #pragma unroll
    for (int msk = 8; msk <= 32; msk <<= 1) {
        a0 += __shfl_xor(a0, msk, 64); a1 += __shfl_xor(a1, msk, 64);
        a2 += __shfl_xor(a2, msk, 64); a3 += __shfl_xor(a3, msk, 64);
        a4 += __shfl_xor(a4, msk, 64); a5 += __shfl_xor(a5, msk, 64);
        a6 += __shfl_xor(a6, msk, 64); a7 += __shfl_xor(a7, msk, 64);
    }

    // self-loop (uniform across all lanes; groups stay identical)
    float selfw = iso[node] * isi[node];
    {
        uint4 u = *(const uint4*)(xin + ((size_t)node << 6) + (chunk << 3));
        const __half2* hp = (const __half2*)&u;
        float2 f0 = __half22float2(hp[0]);
        float2 f1 = __half22float2(hp[1]);
        float2 f2 = __half22float2(hp[2]);
        float2 f3 = __half22float2(hp[3]);
        a0 = fmaf(selfw, f0.x, a0); a1 = fmaf(selfw, f0.y, a1);
        a2 = fmaf(selfw, f1.x, a2); a3 = fmaf(selfw, f1.y, a3);
        a4 = fmaf(selfw, f2.x, a4); a5 = fmaf(selfw, f2.y, a5);
        a6 = fmaf(selfw, f3.x, a6); a7 = fmaf(selfw, f3.y, a7);
    }

    // feat (fp32, stride 50): features 8*chunk .. 8*chunk+7, zero past 49
    float f[8] = {0.f, 0.f, 0.f, 0.f, 0.f, 0.f, 0.f, 0.f};
    int fb = chunk << 3;
    #pragma unroll
    for (int k = 0; k < 4; ++k) {
        int ff = fb + (k << 1);
        if (ff + 1 < D) {            // D even -> pairs fully valid or invalid
            float2 v = *(const float2*)(feat + (size_t)node * D + ff);
            f[k * 2] = v.x; f[k * 2 + 1] = v.y;
        }
    }

    float d0 = a0 - f[0], d1 = a1 - f[1], d2 = a2 - f[2], d3 = a3 - f[3];
    float d4 = a4 - f[4], d5 = a5 - f[5], d6 = a6 - f[6], d7 = a7 - f[7];

    float ssum = d0*d0 + d1*d1 + d2*d2 + d3*d3 + d4*d4 + d5*d5 + d6*d6 + d7*d7;
    ssum += __shfl_xor(ssum, 1, 64);
    ssum += __shfl_xor(ssum, 2, 64);
    ssum += __shfl_xor(ssum, 4, 64);
    float norm = sqrtf(ssum);
    float sc = (norm > 0.0f) ? fmaxf(norm - GLAM, 0.0f) / norm : 0.0f;

    if (lane < 8) {                  // slot 0 writes
        float o0 = f[0] + sc * d0, o1 = f[1] + sc * d1;
        float o2 = f[2] + sc * d2, o3 = f[3] + sc * d3;
        float o4 = f[4] + sc * d4, o5 = f[5] + sc * d5;
        float o6 = f[6] + sc * d6, o7 = f[7] + sc * d7;
        if (!final_iter) {
            __half2 h0 = __float22half2_rn(make_float2(o0, o1));
            __half2 h1 = __float22half2_rn(make_float2(o2, o3));
            __half2 h2 = __float22half2_rn(make_float2(o4, o5));
            __half2 h3 = __float22half2_rn(make_float2(o6, o7));
            uint4 u;
            u.x = *(unsigned*)&h0; u.y = *(unsigned*)&h1;
            u.z = *(unsigned*)&h2; u.w = *(unsigned*)&h3;
            *(uint4*)(hout + ((size_t)node << 6) + (chunk << 3)) = u;
        } else {
            float o[8] = {o0, o1, o2, o3, o4, o5, o6, o7};
            #pragma unroll
            for (int k = 0; k < 4; ++k) {
                int ff = fb + (k << 1);
                if (ff + 1 < D) {
                    float2 v; v.x = o[k * 2]; v.y = o[k * 2 + 1];
                    *(float2*)(fout + (size_t)node * D + ff) = v;
                }
            }
        }
    }
}

extern "C" void kernel_launch(void* const* d_in, const int* in_sizes, int n_in,
                              void* d_out, int out_size, void* d_ws, size_t ws_size,
                              hipStream_t stream) {
    const float* feat = (const float*)d_in[0];
    const float* ew   = (const float*)d_in[1];
    const int* src = (const int*)d_in[2];
    const int* dst = (const int*)d_in[3];

    const int nd = in_sizes[0];      // N * D
    const int n  = nd / D;           // N nodes
    const int e  = in_sizes[1];      // E edges
    const int np = n * PADH;         // padded fp16 element count
    const int nb = (n + (1 << BSHIFT) - 1) >> BSHIFT;   // src buckets (7 for 100k)
    const int nnb = n * nb;

    // workspace layout: 128B-aligned fp16 buffers first
    __half* xpA    = (__half*)d_ws;          // np (fp16, rows 128B-aligned)
    __half* xpB    = xpA + np;               // np
    u64*    pkdeg  = (u64*)(xpB + np);       // n*nb
    u64*    pe     = pkdeg + nnb;            // e  (packed col|wv)
    float*  odeg   = (float*)(pe + e);       // n  -> iso after k_post
    float*  isi    = odeg + n;               // n
    int*    cnt    = (int*)(isi + n);        // n*nb
    int*    rowptr = cnt + nnb;              // n*nb
    int*    rank   = rowptr + nnb;           // e
    int*    bsum   = rank + e;               // 1024
    float*  out    = (float*)d_out;

    const int B = 256;
    const int gI = (nnb + B - 1) / B;
    const int gN = (n + B - 1) / B;
    const int gE = (e + B - 1) / B;
    const int gP = (np + B - 1) / B;
    const int NB = (nnb + SCAN_B - 1) / SCAN_B;

    k_init<<<gI, B, 0, stream>>>(pkdeg, odeg, n, nnb);
    k_deg_hist<<<gE, B, 0, stream>>>(ew, src, dst, pkdeg, odeg, rank, e, nb);
    k_pad<<<gP, B, 0, stream>>>(feat, xpA, n);
    k_post<<<gN, B, 0, stream>>>(pkdeg, odeg, isi, cnt, n, nb);
    k_scan1<<<NB, SCAN_B, 0, stream>>>(cnt, rowptr, bsum, nnb);
    k_scan2<<<1, SCAN_B, 0, stream>>>(bsum, NB);
    k_scan3<<<NB, SCAN_B, 0, stream>>>(rowptr, bsum, nnb);
    k_scatter<<<gE, B, 0, stream>>>(ew, src, dst, odeg, isi, rowptr, rank, pe, e, nb);

    const int wavesPerBlock = B / 64;            // 4
    const int iterGrid = (n + wavesPerBlock - 1) / wavesPerBlock;

    // iter1: xpA -> xpB ; iter2: xpB -> xpA ; iter3: xpA -> d_out (fp32)
    k_iter<<<iterGrid, B, 0, stream>>>(rowptr, pe, xpA, feat, odeg, isi, xpB, out, n, nb, e, 0);
    k_iter<<<iterGrid, B, 0, stream>>>(rowptr, pe, xpB, feat, odeg, isi, xpA, out, n, nb, e, 0);
    k_iter<<<iterGrid, B, 0, stream>>>(rowptr, pe, xpA, feat, odeg, isi, xpA, out, n, nb, e, 1);
}

// Round 11
// 369.707 us; speedup vs baseline: 1.3244x; 1.3244x over previous
//
#include <hip/hip_runtime.h>
#include <hip/hip_bf16.h>
#include <hip/hip_fp16.h>

#define D 50
#define PADH 64                     // fp16 row stride: 128 B = 2 aligned 64B lines
#define GLAM 0.05555555555555555f   // gamma * lambda = (1/(2*0.9)) * 0.1
#define SCAN_B 1024
#define FIXS 16777216.0f            // 2^24 fixed-point scale
#define INV_FIXS (1.0f / 16777216.0f)
#define EPB 4096                    // edges per binning block
#define MAXB 512                    // max buckets (supports n <= 131072)

typedef unsigned long long u64;

// ---- pass 1: per-block LDS histograms over dst-bucket and src-bucket ----
__global__ void k_b1(const int* __restrict__ src, const int* __restrict__ dst,
                     int* __restrict__ mat, int e, int nblk, int nbuk) {
    __shared__ unsigned hd[MAXB], hs[MAXB];
    for (int j = threadIdx.x; j < nbuk; j += blockDim.x) { hd[j] = 0; hs[j] = 0; }
    __syncthreads();
    int base = blockIdx.x * EPB;
    int end = base + EPB; if (end > e) end = e;
    for (int i = base + threadIdx.x; i < end; i += blockDim.x) {
        int t = __builtin_nontemporal_load(dst + i);
        int s = __builtin_nontemporal_load(src + i);
        atomicAdd(&hd[t >> 8], 1u);
        atomicAdd(&hs[s >> 8], 1u);
    }
    __syncthreads();
    for (int j = threadIdx.x; j < nbuk; j += blockDim.x) {
        mat[j * nblk + blockIdx.x] = (int)hd[j];
        mat[(nbuk + j) * nblk + blockIdx.x] = (int)hs[j];
    }
}

// ---- 3-kernel exclusive scan ----
__global__ void k_scan1(const int* __restrict__ cnt, int* __restrict__ out,
                        int* __restrict__ bsum, int n) {
    __shared__ int s[SCAN_B];
    int i = blockIdx.x * SCAN_B + threadIdx.x;
    int v = (i < n) ? cnt[i] : 0;
    s[threadIdx.x] = v; __syncthreads();
    for (int off = 1; off < SCAN_B; off <<= 1) {
        int t = (threadIdx.x >= (unsigned)off) ? s[threadIdx.x - off] : 0;
        __syncthreads();
        s[threadIdx.x] += t; __syncthreads();
    }
    if (i < n) out[i] = s[threadIdx.x] - v;             // exclusive
    if (threadIdx.x == SCAN_B - 1) bsum[blockIdx.x] = s[threadIdx.x];
}

__global__ void k_scan2(int* __restrict__ bsum, int nb) {
    __shared__ int s[SCAN_B];
    int v = (threadIdx.x < (unsigned)nb) ? bsum[threadIdx.x] : 0;
    s[threadIdx.x] = v; __syncthreads();
    for (int off = 1; off < SCAN_B; off <<= 1) {
        int t = (threadIdx.x >= (unsigned)off) ? s[threadIdx.x - off] : 0;
        __syncthreads();
        s[threadIdx.x] += t; __syncthreads();
    }
    if (threadIdx.x < (unsigned)nb) bsum[threadIdx.x] = s[threadIdx.x] - v;  // exclusive
}

__global__ void k_scan3(int* __restrict__ out, const int* __restrict__ bsum, int n) {
    int i = blockIdx.x * SCAN_B + threadIdx.x;
    if (i < n) out[i] += bsum[blockIdx.x];
}

// ---- pass 2: reorder edges into dst-binned (u64) and src-binned (u32) ----
__global__ void k_b2(const float* __restrict__ ew, const int* __restrict__ src,
                     const int* __restrict__ dst, const int* __restrict__ msc,
                     u64* __restrict__ bind, unsigned* __restrict__ bins,
                     int e, int nblk, int nbuk) {
    __shared__ unsigned cd[MAXB], cs[MAXB];
    for (int j = threadIdx.x; j < nbuk; j += blockDim.x) {
        cd[j] = (unsigned)msc[j * nblk + blockIdx.x];
        cs[j] = (unsigned)msc[(nbuk + j) * nblk + blockIdx.x];
    }
    __syncthreads();
    int base = blockIdx.x * EPB;
    int end = base + EPB; if (end > e) end = e;
    for (int i = base + threadIdx.x; i < end; i += blockDim.x) {
        float w = __builtin_nontemporal_load(ew + i);
        int s = __builtin_nontemporal_load(src + i);
        int t = __builtin_nontemporal_load(dst + i);
        unsigned wfix = (unsigned)(w * FIXS + 0.5f);
        if (wfix > 0xFFFFFFu) wfix = 0xFFFFFFu;
        unsigned pd = atomicAdd(&cd[t >> 8], 1u);
        bind[pd] = ((u64)__float_as_uint(w) << 32) | ((unsigned)s << 8) | (unsigned)(t & 255);
        unsigned ps = atomicAdd(&cs[s >> 8], 1u);
        bins[ps - (unsigned)e] = (wfix << 8) | (unsigned)(s & 255);
    }
}

// ---- pass 3: per-bucket exact histograms in LDS -> cnt, isi, iso ----
__global__ void k_hist2(const u64* __restrict__ bind, const unsigned* __restrict__ bins,
                        const int* __restrict__ msc, float* __restrict__ isi,
                        float* __restrict__ iso, int* __restrict__ cnt,
                        int n, int nblk, int nbuk, int e) {
    __shared__ unsigned cl[256], wl[256];
    cl[threadIdx.x] = 0; wl[threadIdx.x] = 0;
    __syncthreads();
    int b = blockIdx.x;                      // 0..2*nbuk-1
    int isSrc = (b >= nbuk);
    int bb = isSrc ? (b - nbuk) : b;
    int start = msc[b * nblk];
    int end = (b + 1 < 2 * nbuk) ? msc[(b + 1) * nblk] : 2 * e;
    if (!isSrc) {
        for (int i = start + threadIdx.x; i < end; i += blockDim.x) {
            u64 r = bind[i];
            unsigned loc = (unsigned)r & 255u;
            float w = __uint_as_float((unsigned)(r >> 32));
            unsigned wfix = (unsigned)(w * FIXS + 0.5f);
            if (wfix > 0xFFFFFFu) wfix = 0xFFFFFFu;
            atomicAdd(&cl[loc], 1u);
            atomicAdd(&wl[loc], wfix);
        }
    } else {
        for (int i = (start - e) + threadIdx.x; i < end - e; i += blockDim.x) {
            unsigned r = bins[i];
            atomicAdd(&wl[r & 255u], r >> 8);
        }
    }
    __syncthreads();
    int node = bb * 256 + threadIdx.x;
    if (node < n) {
        float wsum = 1.0f + (float)wl[threadIdx.x] * INV_FIXS;  // +1 self-loop
        if (!isSrc) {
            isi[node] = rsqrtf(wsum);
            cnt[node] = (int)cl[threadIdx.x];
        } else {
            iso[node] = rsqrtf(wsum);
        }
    }
}

// ---- pass 4: per-bucket fill of dst-CSR pe via LDS cursors ----
__global__ void k_fill(const u64* __restrict__ bind, const int* __restrict__ msc,
                       const int* __restrict__ rowptr, const float* __restrict__ iso,
                       const float* __restrict__ isi, u64* __restrict__ pe,
                       int n, int nblk, int nbuk, int e) {
    __shared__ unsigned cur[256];
    __shared__ float isL[256];
    int b = blockIdx.x;                      // 0..nbuk-1
    int node = b * 256 + threadIdx.x;
    if (node < n) { cur[threadIdx.x] = (unsigned)rowptr[node]; isL[threadIdx.x] = isi[node]; }
    __syncthreads();
    int start = msc[b * nblk];
    int end = (b + 1 < nbuk) ? msc[(b + 1) * nblk] : e;
    for (int i = start + threadIdx.x; i < end; i += blockDim.x) {
        u64 r = bind[i];
        unsigned lo = (unsigned)r;
        unsigned tloc = lo & 255u;
        unsigned s = lo >> 8;
        float w = __uint_as_float((unsigned)(r >> 32));
        float wv = w * iso[s] * isL[tloc];
        unsigned pos = atomicAdd(&cur[tloc], 1u);
        pe[pos] = (u64)s | ((u64)__float_as_uint(wv) << 32);
    }
}

// ---- pad feat (stride 50 fp32) -> xp (stride 64 fp16, zeros in pad) ----
__global__ void k_pad(const float* __restrict__ feat, __half* __restrict__ xp, int n) {
    int i = blockIdx.x * blockDim.x + threadIdx.x;
    if (i < n * PADH) {
        int node = i >> 6, col = i & 63;
        xp[i] = (col < D) ? __float2half_rn(feat[node * D + col]) : __half(0.0f);
    }
}

// ---- fused iteration: 8 edge-slots x 8 lanes x 16B gathers + prox (R8) ----
__global__ void k_iter(const int* __restrict__ rowptr, const int* __restrict__ cnt,
                       const u64* __restrict__ pe, const __half* __restrict__ xin,
                       const float* __restrict__ feat, const float* __restrict__ iso,
                       const float* __restrict__ isi, __half* __restrict__ hout,
                       float* __restrict__ fout, int n, int final_iter) {
    int lane = threadIdx.x & 63;
    int node = blockIdx.x * (blockDim.x >> 6) + (threadIdx.x >> 6);
    if (node >= n) return;

    int slot  = lane >> 3;           // edge slot 0..7
    int chunk = lane & 7;            // 8-feature chunk 0..7

    float a0 = 0.f, a1 = 0.f, a2 = 0.f, a3 = 0.f;
    float a4 = 0.f, a5 = 0.f, a6 = 0.f, a7 = 0.f;

    int beg = rowptr[node], m = cnt[node];

    for (int j0 = 0; j0 < m; j0 += 64) {
        int mm = m - j0; if (mm > 64) mm = 64;
        int c = 0; float ww = 0.0f;
        if (lane < mm) {
            u64 p = pe[beg + j0 + lane];
            c  = (int)(unsigned)(p & 0xffffffffULL);
            ww = __uint_as_float((unsigned)(p >> 32));
        }
        for (int jj = 0; jj < mm; jj += 8) {
            int idx = jj + slot;                 // < 64 always
            int   s = __shfl(c,  idx, 64);
            float w = __shfl(ww, idx, 64);
            if (w != 0.0f) {                     // skips junk tail slots too
                uint4 u = *(const uint4*)(xin + ((size_t)s << 6) + (chunk << 3));
                const __half2* hp = (const __half2*)&u;
                float2 f0 = __half22float2(hp[0]);
                float2 f1 = __half22float2(hp[1]);
                float2 f2 = __half22float2(hp[2]);
                float2 f3 = __half22float2(hp[3]);
                a0 = fmaf(w, f0.x, a0); a1 = fmaf(w, f0.y, a1);
                a2 = fmaf(w, f1.x, a2); a3 = fmaf(w, f1.y, a3);
                a4 = fmaf(w, f2.x, a4); a5 = fmaf(w, f2.y, a5);
                a6 = fmaf(w, f3.x, a6); a7 = fmaf(w, f3.y, a7);
            }
        }
    }

    // combine across the 8 slots (fixed chunk): xor masks 8,16,32
    #pragma unroll
    for (int msk = 8; msk <= 32; msk <<= 1) {
        a0 += __shfl_xor(a0, msk, 64); a1 += __shfl_xor(a1, msk, 64);
        a2 += __shfl_xor(a2, msk, 64); a3 += __shfl_xor(a3, msk, 64);
        a4 += __shfl_xor(a4, msk, 64); a5 += __shfl_xor(a5, msk, 64);
        a6 += __shfl_xor(a6, msk, 64); a7 += __shfl_xor(a7, msk, 64);
    }

    // self-loop (uniform across all lanes; groups stay identical)
    float selfw = iso[node] * isi[node];
    {
        uint4 u = *(const uint4*)(xin + ((size_t)node << 6) + (chunk << 3));
        const __half2* hp = (const __half2*)&u;
        float2 f0 = __half22float2(hp[0]);
        float2 f1 = __half22float2(hp[1]);
        float2 f2 = __half22float2(hp[2]);
        float2 f3 = __half22float2(hp[3]);
        a0 = fmaf(selfw, f0.x, a0); a1 = fmaf(selfw, f0.y, a1);
        a2 = fmaf(selfw, f1.x, a2); a3 = fmaf(selfw, f1.y, a3);
        a4 = fmaf(selfw, f2.x, a4); a5 = fmaf(selfw, f2.y, a5);
        a6 = fmaf(selfw, f3.x, a6); a7 = fmaf(selfw, f3.y, a7);
    }

    // feat (fp32, stride 50): features 8*chunk .. 8*chunk+7, zero past 49
    float f[8] = {0.f, 0.f, 0.f, 0.f, 0.f, 0.f, 0.f, 0.f};
    int fb = chunk << 3;
    #pragma unroll
    for (int k = 0; k < 4; ++k) {
        int ff = fb + (k << 1);
        if (ff + 1 < D) {            // D even -> pairs fully valid or invalid
            float2 v = *(const float2*)(feat + (size_t)node * D + ff);
            f[k * 2] = v.x; f[k * 2 + 1] = v.y;
        }
    }

    float d0 = a0 - f[0], d1 = a1 - f[1], d2 = a2 - f[2], d3 = a3 - f[3];
    float d4 = a4 - f[4], d5 = a5 - f[5], d6 = a6 - f[6], d7 = a7 - f[7];

    float ssum = d0*d0 + d1*d1 + d2*d2 + d3*d3 + d4*d4 + d5*d5 + d6*d6 + d7*d7;
    ssum += __shfl_xor(ssum, 1, 64);
    ssum += __shfl_xor(ssum, 2, 64);
    ssum += __shfl_xor(ssum, 4, 64);
    float norm = sqrtf(ssum);
    float sc = (norm > 0.0f) ? fmaxf(norm - GLAM, 0.0f) / norm : 0.0f;

    if (lane < 8) {                  // slot 0 writes
        float o0 = f[0] + sc * d0, o1 = f[1] + sc * d1;
        float o2 = f[2] + sc * d2, o3 = f[3] + sc * d3;
        float o4 = f[4] + sc * d4, o5 = f[5] + sc * d5;
        float o6 = f[6] + sc * d6, o7 = f[7] + sc * d7;
        if (!final_iter) {
            __half2 h0 = __float22half2_rn(make_float2(o0, o1));
            __half2 h1 = __float22half2_rn(make_float2(o2, o3));
            __half2 h2 = __float22half2_rn(make_float2(o4, o5));
            __half2 h3 = __float22half2_rn(make_float2(o6, o7));
            uint4 u;
            u.x = *(unsigned*)&h0; u.y = *(unsigned*)&h1;
            u.z = *(unsigned*)&h2; u.w = *(unsigned*)&h3;
            *(uint4*)(hout + ((size_t)node << 6) + (chunk << 3)) = u;
        } else {
            float o[8] = {o0, o1, o2, o3, o4, o5, o6, o7};
            #pragma unroll
            for (int k = 0; k < 4; ++k) {
                int ff = fb + (k << 1);
                if (ff + 1 < D) {
                    float2 v; v.x = o[k * 2]; v.y = o[k * 2 + 1];
                    *(float2*)(fout + (size_t)node * D + ff) = v;
                }
            }
        }
    }
}

extern "C" void kernel_launch(void* const* d_in, const int* in_sizes, int n_in,
                              void* d_out, int out_size, void* d_ws, size_t ws_size,
                              hipStream_t stream) {
    const float* feat = (const float*)d_in[0];
    const float* ew   = (const float*)d_in[1];
    const int* src = (const int*)d_in[2];
    const int* dst = (const int*)d_in[3];

    const int nd = in_sizes[0];      // N * D
    const int n  = nd / D;           // N nodes
    const int e  = in_sizes[1];      // E edges
    const int np = n * PADH;         // padded fp16 element count

    const int nbuk = (n + 255) >> 8;            // 256-node buckets (391 @100k)
    const int nblk = (e + EPB - 1) / EPB;       // binning blocks (391 @1.6M)
    const int nm   = 2 * nbuk * nblk;           // count-matrix entries

    // workspace layout: 128B-aligned fp16 buffers first
    __half*   xpA    = (__half*)d_ws;           // np (fp16, rows 128B-aligned)
    __half*   xpB    = xpA + np;                // np
    u64*      bind   = (u64*)(xpB + np);        // e   (dst-binned records)
    u64*      pe     = bind + e;                // e   (final CSR: col|wv)
    unsigned* bins   = (unsigned*)(pe + e);     // e   (src-binned records)
    int*      mat    = (int*)(bins + e);        // nm
    int*      msc    = mat + nm;                // nm
    float*    isi    = (float*)(msc + nm);      // n
    float*    iso    = isi + n;                 // n
    int*      cnt    = (int*)(iso + n);         // n
    int*      rowptr = cnt + n;                 // n
    int*      bsum   = rowptr + n;              // 1024
    float*    out    = (float*)d_out;

    const int B = 256;
    const int gP  = (np + B - 1) / B;
    const int NBm = (nm + SCAN_B - 1) / SCAN_B;
    const int NBc = (n + SCAN_B - 1) / SCAN_B;

    k_b1<<<nblk, B, 0, stream>>>(src, dst, mat, e, nblk, nbuk);
    k_scan1<<<NBm, SCAN_B, 0, stream>>>(mat, msc, bsum, nm);
    k_scan2<<<1, SCAN_B, 0, stream>>>(bsum, NBm);
    k_scan3<<<NBm, SCAN_B, 0, stream>>>(msc, bsum, nm);
    k_b2<<<nblk, B, 0, stream>>>(ew, src, dst, msc, bind, bins, e, nblk, nbuk);
    k_hist2<<<2 * nbuk, B, 0, stream>>>(bind, bins, msc, isi, iso, cnt, n, nblk, nbuk, e);
    k_scan1<<<NBc, SCAN_B, 0, stream>>>(cnt, rowptr, bsum, n);
    k_scan2<<<1, SCAN_B, 0, stream>>>(bsum, NBc);
    k_scan3<<<NBc, SCAN_B, 0, stream>>>(rowptr, bsum, n);
    k_fill<<<nbuk, B, 0, stream>>>(bind, msc, rowptr, iso, isi, pe, n, nblk, nbuk, e);
    k_pad<<<gP, B, 0, stream>>>(feat, xpA, n);

    const int wavesPerBlock = B / 64;            // 4
    const int iterGrid = (n + wavesPerBlock - 1) / wavesPerBlock;

    // iter1: xpA -> xpB ; iter2: xpB -> xpA ; iter3: xpA -> d_out (fp32)
    k_iter<<<iterGrid, B, 0, stream>>>(rowptr, cnt, pe, xpA, feat, iso, isi, xpB, out, n, 0);
    k_iter<<<iterGrid, B, 0, stream>>>(rowptr, cnt, pe, xpB, feat, iso, isi, xpA, out, n, 0);
    k_iter<<<iterGrid, B, 0, stream>>>(rowptr, cnt, pe, xpA, feat, iso, isi, xpA, out, n, 1);
}

// Round 12
// 353.194 us; speedup vs baseline: 1.3864x; 1.0468x over previous
//
#include <hip/hip_runtime.h>
#include <hip/hip_bf16.h>
#include <hip/hip_fp16.h>

#define D 50
#define PADH 64                     // fp16 row stride: 128 B = 2 aligned 64B lines
#define GLAM 0.05555555555555555f   // gamma * lambda = (1/(2*0.9)) * 0.1
#define SCAN_B 1024
#define FIXS 8388608.0f             // 2^23 fixed-point scale
#define INV_FIXS (1.0f / 8388608.0f)
#define EPB 4096                    // edges per binning block
#define BSH 9                       // 512-node buckets
#define BMSK 511u
#define BT 512                      // threads for hist2/fill
#define MAXB 256                    // max buckets (supports n <= 131072)

typedef unsigned long long u64;

// ---- pass 1: per-block LDS histograms over dst-bucket and src-bucket ----
__global__ void k_b1(const int* __restrict__ src, const int* __restrict__ dst,
                     int* __restrict__ mat, int e, int nblk, int nbuk) {
    __shared__ unsigned hd[MAXB], hs[MAXB];
    for (int j = threadIdx.x; j < nbuk; j += blockDim.x) { hd[j] = 0; hs[j] = 0; }
    __syncthreads();
    int base = blockIdx.x * EPB;
    int end = base + EPB; if (end > e) end = e;
    for (int i = base + threadIdx.x; i < end; i += blockDim.x) {
        int t = __builtin_nontemporal_load(dst + i);
        int s = __builtin_nontemporal_load(src + i);
        atomicAdd(&hd[t >> BSH], 1u);
        atomicAdd(&hs[s >> BSH], 1u);
    }
    __syncthreads();
    for (int j = threadIdx.x; j < nbuk; j += blockDim.x) {
        mat[j * nblk + blockIdx.x] = (int)hd[j];
        mat[(nbuk + j) * nblk + blockIdx.x] = (int)hs[j];
    }
}

// ---- 3-kernel exclusive scan ----
__global__ void k_scan1(const int* __restrict__ cnt, int* __restrict__ out,
                        int* __restrict__ bsum, int n) {
    __shared__ int s[SCAN_B];
    int i = blockIdx.x * SCAN_B + threadIdx.x;
    int v = (i < n) ? cnt[i] : 0;
    s[threadIdx.x] = v; __syncthreads();
    for (int off = 1; off < SCAN_B; off <<= 1) {
        int t = (threadIdx.x >= (unsigned)off) ? s[threadIdx.x - off] : 0;
        __syncthreads();
        s[threadIdx.x] += t; __syncthreads();
    }
    if (i < n) out[i] = s[threadIdx.x] - v;             // exclusive
    if (threadIdx.x == SCAN_B - 1) bsum[blockIdx.x] = s[threadIdx.x];
}

__global__ void k_scan2(int* __restrict__ bsum, int nb) {
    __shared__ int s[SCAN_B];
    int v = (threadIdx.x < (unsigned)nb) ? bsum[threadIdx.x] : 0;
    s[threadIdx.x] = v; __syncthreads();
    for (int off = 1; off < SCAN_B; off <<= 1) {
        int t = (threadIdx.x >= (unsigned)off) ? s[threadIdx.x - off] : 0;
        __syncthreads();
        s[threadIdx.x] += t; __syncthreads();
    }
    if (threadIdx.x < (unsigned)nb) bsum[threadIdx.x] = s[threadIdx.x] - v;  // exclusive
}

__global__ void k_scan3(int* __restrict__ out, const int* __restrict__ bsum, int n) {
    int i = blockIdx.x * SCAN_B + threadIdx.x;
    if (i < n) out[i] += bsum[blockIdx.x];
}

// ---- pass 2: reorder edges into dst-binned (u64) and src-binned (u32) ----
__global__ void k_b2(const float* __restrict__ ew, const int* __restrict__ src,
                     const int* __restrict__ dst, const int* __restrict__ msc,
                     u64* __restrict__ bind, unsigned* __restrict__ bins,
                     int e, int nblk, int nbuk) {
    __shared__ unsigned cd[MAXB], cs[MAXB];
    for (int j = threadIdx.x; j < nbuk; j += blockDim.x) {
        cd[j] = (unsigned)msc[j * nblk + blockIdx.x];
        cs[j] = (unsigned)msc[(nbuk + j) * nblk + blockIdx.x];
    }
    __syncthreads();
    int base = blockIdx.x * EPB;
    int end = base + EPB; if (end > e) end = e;
    for (int i = base + threadIdx.x; i < end; i += blockDim.x) {
        float w = __builtin_nontemporal_load(ew + i);
        int s = __builtin_nontemporal_load(src + i);
        int t = __builtin_nontemporal_load(dst + i);
        unsigned wfix = (unsigned)(w * FIXS + 0.5f);
        if (wfix > 0x7FFFFFu) wfix = 0x7FFFFFu;
        unsigned pd = atomicAdd(&cd[t >> BSH], 1u);
        bind[pd] = ((u64)__float_as_uint(w) << 32)
                 | ((unsigned)s << BSH) | (unsigned)(t & BMSK);
        unsigned ps = atomicAdd(&cs[s >> BSH], 1u);
        bins[ps - (unsigned)e] = (wfix << BSH) | (unsigned)(s & BMSK);
    }
}

// ---- pass 3: per-bucket exact histograms in LDS -> cnt, isi, iso ----
__global__ void k_hist2(const u64* __restrict__ bind, const unsigned* __restrict__ bins,
                        const int* __restrict__ msc, float* __restrict__ isi,
                        float* __restrict__ iso, int* __restrict__ cnt,
                        int n, int nblk, int nbuk, int e) {
    __shared__ unsigned cl[BT], wl[BT];
    cl[threadIdx.x] = 0; wl[threadIdx.x] = 0;
    __syncthreads();
    int b = blockIdx.x;                      // 0..2*nbuk-1
    int isSrc = (b >= nbuk);
    int bb = isSrc ? (b - nbuk) : b;
    int start = msc[b * nblk];
    int end = (b + 1 < 2 * nbuk) ? msc[(b + 1) * nblk] : 2 * e;
    if (!isSrc) {
        for (int i = start + threadIdx.x; i < end; i += blockDim.x) {
            u64 r = bind[i];
            unsigned loc = (unsigned)r & BMSK;
            float w = __uint_as_float((unsigned)(r >> 32));
            unsigned wfix = (unsigned)(w * FIXS + 0.5f);
            if (wfix > 0x7FFFFFu) wfix = 0x7FFFFFu;
            atomicAdd(&cl[loc], 1u);
            atomicAdd(&wl[loc], wfix);
        }
    } else {
        for (int i = (start - e) + threadIdx.x; i < end - e; i += blockDim.x) {
            unsigned r = bins[i];
            atomicAdd(&wl[r & BMSK], r >> BSH);
        }
    }
    __syncthreads();
    int node = bb * BT + threadIdx.x;
    if (node < n) {
        float wsum = 1.0f + (float)wl[threadIdx.x] * INV_FIXS;  // +1 self-loop
        if (!isSrc) {
            isi[node] = rsqrtf(wsum);
            cnt[node] = (int)cl[threadIdx.x];
        } else {
            iso[node] = rsqrtf(wsum);
        }
    }
}

// ---- pass 4: per-bucket fill of dst-CSR pe via LDS cursors ----
__global__ void k_fill(const u64* __restrict__ bind, const int* __restrict__ msc,
                       const int* __restrict__ rowptr, const float* __restrict__ iso,
                       const float* __restrict__ isi, u64* __restrict__ pe,
                       int n, int nblk, int nbuk, int e) {
    __shared__ unsigned cur[BT];
    __shared__ float isL[BT];
    int b = blockIdx.x;                      // 0..nbuk-1
    int node = b * BT + threadIdx.x;
    if (node < n) { cur[threadIdx.x] = (unsigned)rowptr[node]; isL[threadIdx.x] = isi[node]; }
    __syncthreads();
    int start = msc[b * nblk];
    int end = (b + 1 < nbuk) ? msc[(b + 1) * nblk] : e;
    for (int i = start + threadIdx.x; i < end; i += blockDim.x) {
        u64 r = bind[i];
        unsigned lo = (unsigned)r;
        unsigned tloc = lo & BMSK;
        unsigned s = lo >> BSH;
        float w = __uint_as_float((unsigned)(r >> 32));
        float wv = w * iso[s] * isL[tloc];
        unsigned pos = atomicAdd(&cur[tloc], 1u);
        pe[pos] = (u64)s | ((u64)__float_as_uint(wv) << 32);
    }
}

// ---- pad feat (stride 50 fp32) -> xp (stride 64 fp16, zeros in pad) ----
__global__ void k_pad(const float* __restrict__ feat, __half* __restrict__ xp, int n) {
    int i = blockIdx.x * blockDim.x + threadIdx.x;
    if (i < n * PADH) {
        int node = i >> 6, col = i & 63;
        xp[i] = (col < D) ? __float2half_rn(feat[node * D + col]) : __half(0.0f);
    }
}

// ---- fused iteration: 8 edge-slots x 8 lanes x 16B gathers + prox (R8) ----
__global__ void k_iter(const int* __restrict__ rowptr, const int* __restrict__ cnt,
                       const u64* __restrict__ pe, const __half* __restrict__ xin,
                       const float* __restrict__ feat, const float* __restrict__ iso,
                       const float* __restrict__ isi, __half* __restrict__ hout,
                       float* __restrict__ fout, int n, int final_iter) {
    int lane = threadIdx.x & 63;
    int node = blockIdx.x * (blockDim.x >> 6) + (threadIdx.x >> 6);
    if (node >= n) return;

    int slot  = lane >> 3;           // edge slot 0..7
    int chunk = lane & 7;            // 8-feature chunk 0..7

    float a0 = 0.f, a1 = 0.f, a2 = 0.f, a3 = 0.f;
    float a4 = 0.f, a5 = 0.f, a6 = 0.f, a7 = 0.f;

    int beg = rowptr[node], m = cnt[node];

    for (int j0 = 0; j0 < m; j0 += 64) {
        int mm = m - j0; if (mm > 64) mm = 64;
        int c = 0; float ww = 0.0f;
        if (lane < mm) {
            u64 p = pe[beg + j0 + lane];
            c  = (int)(unsigned)(p & 0xffffffffULL);
            ww = __uint_as_float((unsigned)(p >> 32));
        }
        for (int jj = 0; jj < mm; jj += 8) {
            int idx = jj + slot;                 // < 64 always
            int   s = __shfl(c,  idx, 64);
            float w = __shfl(ww, idx, 64);
            if (w != 0.0f) {                     // skips junk tail slots too
                uint4 u = *(const uint4*)(xin + ((size_t)s << 6) + (chunk << 3));
                const __half2* hp = (const __half2*)&u;
                float2 f0 = __half22float2(hp[0]);
                float2 f1 = __half22float2(hp[1]);
                float2 f2 = __half22float2(hp[2]);
                float2 f3 = __half22float2(hp[3]);
                a0 = fmaf(w, f0.x, a0); a1 = fmaf(w, f0.y, a1);
                a2 = fmaf(w, f1.x, a2); a3 = fmaf(w, f1.y, a3);
                a4 = fmaf(w, f2.x, a4); a5 = fmaf(w, f2.y, a5);
                a6 = fmaf(w, f3.x, a6); a7 = fmaf(w, f3.y, a7);
            }
        }
    }

    // combine across the 8 slots (fixed chunk): xor masks 8,16,32
    #pragma unroll
    for (int msk = 8; msk <= 32; msk <<= 1) {
        a0 += __shfl_xor(a0, msk, 64); a1 += __shfl_xor(a1, msk, 64);
        a2 += __shfl_xor(a2, msk, 64); a3 += __shfl_xor(a3, msk, 64);
        a4 += __shfl_xor(a4, msk, 64); a5 += __shfl_xor(a5, msk, 64);
        a6 += __shfl_xor(a6, msk, 64); a7 += __shfl_xor(a7, msk, 64);
    }

    // self-loop (uniform across all lanes; groups stay identical)
    float selfw = iso[node] * isi[node];
    {
        uint4 u = *(const uint4*)(xin + ((size_t)node << 6) + (chunk << 3));
        const __half2* hp = (const __half2*)&u;
        float2 f0 = __half22float2(hp[0]);
        float2 f1 = __half22float2(hp[1]);
        float2 f2 = __half22float2(hp[2]);
        float2 f3 = __half22float2(hp[3]);
        a0 = fmaf(selfw, f0.x, a0); a1 = fmaf(selfw, f0.y, a1);
        a2 = fmaf(selfw, f1.x, a2); a3 = fmaf(selfw, f1.y, a3);
        a4 = fmaf(selfw, f2.x, a4); a5 = fmaf(selfw, f2.y, a5);
        a6 = fmaf(selfw, f3.x, a6); a7 = fmaf(selfw, f3.y, a7);
    }

    // feat (fp32, stride 50): features 8*chunk .. 8*chunk+7, zero past 49
    float f[8] = {0.f, 0.f, 0.f, 0.f, 0.f, 0.f, 0.f, 0.f};
    int fb = chunk << 3;
    #pragma unroll
    for (int k = 0; k < 4; ++k) {
        int ff = fb + (k << 1);
        if (ff + 1 < D) {            // D even -> pairs fully valid or invalid
            float2 v = *(const float2*)(feat + (size_t)node * D + ff);
            f[k * 2] = v.x; f[k * 2 + 1] = v.y;
        }
    }

    float d0 = a0 - f[0], d1 = a1 - f[1], d2 = a2 - f[2], d3 = a3 - f[3];
    float d4 = a4 - f[4], d5 = a5 - f[5], d6 = a6 - f[6], d7 = a7 - f[7];

    float ssum = d0*d0 + d1*d1 + d2*d2 + d3*d3 + d4*d4 + d5*d5 + d6*d6 + d7*d7;
    ssum += __shfl_xor(ssum, 1, 64);
    ssum += __shfl_xor(ssum, 2, 64);
    ssum += __shfl_xor(ssum, 4, 64);
    float norm = sqrtf(ssum);
    float sc = (norm > 0.0f) ? fmaxf(norm - GLAM, 0.0f) / norm : 0.0f;

    if (lane < 8) {                  // slot 0 writes
        float o0 = f[0] + sc * d0, o1 = f[1] + sc * d1;
        float o2 = f[2] + sc * d2, o3 = f[3] + sc * d3;
        float o4 = f[4] + sc * d4, o5 = f[5] + sc * d5;
        float o6 = f[6] + sc * d6, o7 = f[7] + sc * d7;
        if (!final_iter) {
            __half2 h0 = __float22half2_rn(make_float2(o0, o1));
            __half2 h1 = __float22half2_rn(make_float2(o2, o3));
            __half2 h2 = __float22half2_rn(make_float2(o4, o5));
            __half2 h3 = __float22half2_rn(make_float2(o6, o7));
            uint4 u;
            u.x = *(unsigned*)&h0; u.y = *(unsigned*)&h1;
            u.z = *(unsigned*)&h2; u.w = *(unsigned*)&h3;
            *(uint4*)(hout + ((size_t)node << 6) + (chunk << 3)) = u;
        } else {
            float o[8] = {o0, o1, o2, o3, o4, o5, o6, o7};
            #pragma unroll
            for (int k = 0; k < 4; ++k) {
                int ff = fb + (k << 1);
                if (ff + 1 < D) {
                    float2 v; v.x = o[k * 2]; v.y = o[k * 2 + 1];
                    *(float2*)(fout + (size_t)node * D + ff) = v;
                }
            }
        }
    }
}

extern "C" void kernel_launch(void* const* d_in, const int* in_sizes, int n_in,
                              void* d_out, int out_size, void* d_ws, size_t ws_size,
                              hipStream_t stream) {
    const float* feat = (const float*)d_in[0];
    const float* ew   = (const float*)d_in[1];
    const int* src = (const int*)d_in[2];
    const int* dst = (const int*)d_in[3];

    const int nd = in_sizes[0];      // N * D
    const int n  = nd / D;           // N nodes
    const int e  = in_sizes[1];      // E edges
    const int np = n * PADH;         // padded fp16 element count

    const int nbuk = (n + BT - 1) / BT;         // 512-node buckets (196 @100k)
    const int nblk = (e + EPB - 1) / EPB;       // binning blocks (391 @1.6M)
    const int nm   = 2 * nbuk * nblk;           // count-matrix entries

    // workspace layout: 128B-aligned fp16 buffers first
    __half*   xpA    = (__half*)d_ws;           // np (fp16, rows 128B-aligned)
    __half*   xpB    = xpA + np;                // np
    u64*      bind   = (u64*)(xpB + np);        // e   (dst-binned records)
    u64*      pe     = bind + e;                // e   (final CSR: col|wv)
    unsigned* bins   = (unsigned*)(pe + e);     // e   (src-binned records)
    int*      mat    = (int*)(bins + e);        // nm
    int*      msc    = mat + nm;                // nm
    float*    isi    = (float*)(msc + nm);      // n
    float*    iso    = isi + n;                 // n
    int*      cnt    = (int*)(iso + n);         // n
    int*      rowptr = cnt + n;                 // n
    int*      bsum   = rowptr + n;              // 1024
    float*    out    = (float*)d_out;

    const int B = 256;
    const int gP  = (np + B - 1) / B;
    const int NBm = (nm + SCAN_B - 1) / SCAN_B;
    const int NBc = (n + SCAN_B - 1) / SCAN_B;

    k_b1<<<nblk, B, 0, stream>>>(src, dst, mat, e, nblk, nbuk);
    k_scan1<<<NBm, SCAN_B, 0, stream>>>(mat, msc, bsum, nm);
    k_scan2<<<1, SCAN_B, 0, stream>>>(bsum, NBm);
    k_scan3<<<NBm, SCAN_B, 0, stream>>>(msc, bsum, nm);
    k_b2<<<nblk, B, 0, stream>>>(ew, src, dst, msc, bind, bins, e, nblk, nbuk);
    k_hist2<<<2 * nbuk, BT, 0, stream>>>(bind, bins, msc, isi, iso, cnt, n, nblk, nbuk, e);
    k_scan1<<<NBc, SCAN_B, 0, stream>>>(cnt, rowptr, bsum, n);
    k_scan2<<<1, SCAN_B, 0, stream>>>(bsum, NBc);
    k_scan3<<<NBc, SCAN_B, 0, stream>>>(rowptr, bsum, n);
    k_fill<<<nbuk, BT, 0, stream>>>(bind, msc, rowptr, iso, isi, pe, n, nblk, nbuk, e);
    k_pad<<<gP, B, 0, stream>>>(feat, xpA, n);

    const int wavesPerBlock = B / 64;            // 4
    const int iterGrid = (n + wavesPerBlock - 1) / wavesPerBlock;

    // iter1: xpA -> xpB ; iter2: xpB -> xpA ; iter3: xpA -> d_out (fp32)
    k_iter<<<iterGrid, B, 0, stream>>>(rowptr, cnt, pe, xpA, feat, iso, isi, xpB, out, n, 0);
    k_iter<<<iterGrid, B, 0, stream>>>(rowptr, cnt, pe, xpB, feat, iso, isi, xpA, out, n, 0);
    k_iter<<<iterGrid, B, 0, stream>>>(rowptr, cnt, pe, xpA, feat, iso, isi, xpA, out, n, 1);
}

// Round 13
// 297.426 us; speedup vs baseline: 1.6463x; 1.1875x over previous
//
#include <hip/hip_runtime.h>
#include <hip/hip_bf16.h>
#include <hip/hip_fp16.h>

#define D 50
#define PADH 64                     // fp16 row stride: 128 B = 2 aligned 64B lines
#define GLAM 0.05555555555555555f   // gamma * lambda = (1/(2*0.9)) * 0.1
#define SCAN_B 1024
#define FIXS 8388608.0f             // 2^23 fixed-point scale
#define INV_FIXS (1.0f / 8388608.0f)
#define EPB 4096                    // edges per binning block
#define BSH 9                       // 512-node buckets
#define BMSK 511u
#define BT 512                      // threads for hist2/fill
#define MAXB 256                    // max buckets (supports n <= 131072)

typedef unsigned long long u64;

// ---- pass 1: per-block LDS histograms over dst-bucket and src-bucket ----
__global__ void k_b1(const int* __restrict__ src, const int* __restrict__ dst,
                     int* __restrict__ mat, int e, int nblk, int nbuk) {
    __shared__ unsigned hd[MAXB], hs[MAXB];
    for (int j = threadIdx.x; j < nbuk; j += blockDim.x) { hd[j] = 0; hs[j] = 0; }
    __syncthreads();
    int base = blockIdx.x * EPB;
    int end = base + EPB; if (end > e) end = e;
    for (int i = base + threadIdx.x; i < end; i += blockDim.x) {
        int t = __builtin_nontemporal_load(dst + i);
        int s = __builtin_nontemporal_load(src + i);
        atomicAdd(&hd[t >> BSH], 1u);
        atomicAdd(&hs[s >> BSH], 1u);
    }
    __syncthreads();
    for (int j = threadIdx.x; j < nbuk; j += blockDim.x) {
        mat[j * nblk + blockIdx.x] = (int)hd[j];
        mat[(nbuk + j) * nblk + blockIdx.x] = (int)hs[j];
    }
}

// ---- 3-kernel exclusive scan ----
__global__ void k_scan1(const int* __restrict__ cnt, int* __restrict__ out,
                        int* __restrict__ bsum, int n) {
    __shared__ int s[SCAN_B];
    int i = blockIdx.x * SCAN_B + threadIdx.x;
    int v = (i < n) ? cnt[i] : 0;
    s[threadIdx.x] = v; __syncthreads();
    for (int off = 1; off < SCAN_B; off <<= 1) {
        int t = (threadIdx.x >= (unsigned)off) ? s[threadIdx.x - off] : 0;
        __syncthreads();
        s[threadIdx.x] += t; __syncthreads();
    }
    if (i < n) out[i] = s[threadIdx.x] - v;             // exclusive
    if (threadIdx.x == SCAN_B - 1) bsum[blockIdx.x] = s[threadIdx.x];
}

__global__ void k_scan2(int* __restrict__ bsum, int nb) {
    __shared__ int s[SCAN_B];
    int v = (threadIdx.x < (unsigned)nb) ? bsum[threadIdx.x] : 0;
    s[threadIdx.x] = v; __syncthreads();
    for (int off = 1; off < SCAN_B; off <<= 1) {
        int t = (threadIdx.x >= (unsigned)off) ? s[threadIdx.x - off] : 0;
        __syncthreads();
        s[threadIdx.x] += t; __syncthreads();
    }
    if (threadIdx.x < (unsigned)nb) bsum[threadIdx.x] = s[threadIdx.x] - v;  // exclusive
}

__global__ void k_scan3(int* __restrict__ out, const int* __restrict__ bsum, int n) {
    int i = blockIdx.x * SCAN_B + threadIdx.x;
    if (i < n) out[i] += bsum[blockIdx.x];
}

// ---- pass 2: reorder edges into dst-binned (u64) and src-binned (u32) ----
__global__ void k_b2(const float* __restrict__ ew, const int* __restrict__ src,
                     const int* __restrict__ dst, const int* __restrict__ msc,
                     u64* __restrict__ bind, unsigned* __restrict__ bins,
                     int e, int nblk, int nbuk) {
    __shared__ unsigned cd[MAXB], cs[MAXB];
    for (int j = threadIdx.x; j < nbuk; j += blockDim.x) {
        cd[j] = (unsigned)msc[j * nblk + blockIdx.x];
        cs[j] = (unsigned)msc[(nbuk + j) * nblk + blockIdx.x];
    }
    __syncthreads();
    int base = blockIdx.x * EPB;
    int end = base + EPB; if (end > e) end = e;
    for (int i = base + threadIdx.x; i < end; i += blockDim.x) {
        float w = __builtin_nontemporal_load(ew + i);
        int s = __builtin_nontemporal_load(src + i);
        int t = __builtin_nontemporal_load(dst + i);
        unsigned wfix = (unsigned)(w * FIXS + 0.5f);
        if (wfix > 0x7FFFFFu) wfix = 0x7FFFFFu;
        unsigned pd = atomicAdd(&cd[t >> BSH], 1u);
        bind[pd] = ((u64)__float_as_uint(w) << 32)
                 | ((unsigned)s << BSH) | (unsigned)(t & BMSK);
        unsigned ps = atomicAdd(&cs[s >> BSH], 1u);
        bins[ps - (unsigned)e] = (wfix << BSH) | (unsigned)(s & BMSK);
    }
}

// ---- pass 3: per-bucket exact histograms in LDS -> cnt, isi, iso ----
__global__ void k_hist2(const u64* __restrict__ bind, const unsigned* __restrict__ bins,
                        const int* __restrict__ msc, float* __restrict__ isi,
                        float* __restrict__ iso, int* __restrict__ cnt,
                        int n, int nblk, int nbuk, int e) {
    __shared__ unsigned cl[BT], wl[BT];
    cl[threadIdx.x] = 0; wl[threadIdx.x] = 0;
    __syncthreads();
    int b = blockIdx.x;                      // 0..2*nbuk-1
    int isSrc = (b >= nbuk);
    int bb = isSrc ? (b - nbuk) : b;
    int start = msc[b * nblk];
    int end = (b + 1 < 2 * nbuk) ? msc[(b + 1) * nblk] : 2 * e;
    if (!isSrc) {
        for (int i = start + threadIdx.x; i < end; i += blockDim.x) {
            u64 r = bind[i];
            unsigned loc = (unsigned)r & BMSK;
            float w = __uint_as_float((unsigned)(r >> 32));
            unsigned wfix = (unsigned)(w * FIXS + 0.5f);
            if (wfix > 0x7FFFFFu) wfix = 0x7FFFFFu;
            atomicAdd(&cl[loc], 1u);
            atomicAdd(&wl[loc], wfix);
        }
    } else {
        for (int i = (start - e) + threadIdx.x; i < end - e; i += blockDim.x) {
            unsigned r = bins[i];
            atomicAdd(&wl[r & BMSK], r >> BSH);
        }
    }
    __syncthreads();
    int node = bb * BT + threadIdx.x;
    if (node < n) {
        float wsum = 1.0f + (float)wl[threadIdx.x] * INV_FIXS;  // +1 self-loop
        if (!isSrc) {
            isi[node] = rsqrtf(wsum);
            cnt[node] = (int)cl[threadIdx.x];
        } else {
            iso[node] = rsqrtf(wsum);
        }
    }
}

// ---- pass 4: per-bucket fill of dst-CSR pe via LDS cursors ----
__global__ void k_fill(const u64* __restrict__ bind, const int* __restrict__ msc,
                       const int* __restrict__ rowptr, const float* __restrict__ iso,
                       const float* __restrict__ isi, u64* __restrict__ pe,
                       int n, int nblk, int nbuk, int e) {
    __shared__ unsigned cur[BT];
    __shared__ float isL[BT];
    int b = blockIdx.x;                      // 0..nbuk-1
    int node = b * BT + threadIdx.x;
    if (node < n) { cur[threadIdx.x] = (unsigned)rowptr[node]; isL[threadIdx.x] = isi[node]; }
    __syncthreads();
    int start = msc[b * nblk];
    int end = (b + 1 < nbuk) ? msc[(b + 1) * nblk] : e;
    for (int i = start + threadIdx.x; i < end; i += blockDim.x) {
        u64 r = bind[i];
        unsigned lo = (unsigned)r;
        unsigned tloc = lo & BMSK;
        unsigned s = lo >> BSH;
        float w = __uint_as_float((unsigned)(r >> 32));
        float wv = w * iso[s] * isL[tloc];
        unsigned pos = atomicAdd(&cur[tloc], 1u);
        pe[pos] = (u64)s | ((u64)__float_as_uint(wv) << 32);
    }
}

// ---- pad feat (stride 50 fp32) -> xp (stride 64 fp16, zeros in pad) ----
__global__ void k_pad(const float* __restrict__ feat, __half* __restrict__ xp, int n) {
    int i = blockIdx.x * blockDim.x + threadIdx.x;
    if (i < n * PADH) {
        int node = i >> 6, col = i & 63;
        xp[i] = (col < D) ? __float2half_rn(feat[node * D + col]) : __half(0.0f);
    }
}

// ---- fused iteration: 8 nodes per wave, 8 lanes per node, 16B gathers ----
__global__ void k_iter(const int* __restrict__ rowptr, const int* __restrict__ cnt,
                       const u64* __restrict__ pe, const __half* __restrict__ xin,
                       const float* __restrict__ feat, const float* __restrict__ iso,
                       const float* __restrict__ isi, __half* __restrict__ hout,
                       float* __restrict__ fout, int n, int final_iter) {
    int lane = threadIdx.x & 63;
    int c    = lane & 7;             // feature chunk 0..7 within group
    int waveId = (blockIdx.x * blockDim.x + threadIdx.x) >> 6;
    int node = waveId * 8 + (lane >> 3);
    if (node >= n) return;

    float a0 = 0.f, a1 = 0.f, a2 = 0.f, a3 = 0.f;
    float a4 = 0.f, a5 = 0.f, a6 = 0.f, a7 = 0.f;

    int beg = rowptr[node], m = cnt[node];

    int j = 0;
    for (; j + 2 <= m; j += 2) {
        u64 p0 = pe[beg + j];
        u64 p1 = pe[beg + j + 1];
        unsigned s0 = (unsigned)p0;
        float    w0 = __uint_as_float((unsigned)(p0 >> 32));
        unsigned s1 = (unsigned)p1;
        float    w1 = __uint_as_float((unsigned)(p1 >> 32));
        uint4 u0 = *(const uint4*)(xin + ((size_t)s0 << 6) + (c << 3));
        uint4 u1 = *(const uint4*)(xin + ((size_t)s1 << 6) + (c << 3));
        {
            const __half2* hp = (const __half2*)&u0;
            float2 f0 = __half22float2(hp[0]);
            float2 f1 = __half22float2(hp[1]);
            float2 f2 = __half22float2(hp[2]);
            float2 f3 = __half22float2(hp[3]);
            a0 = fmaf(w0, f0.x, a0); a1 = fmaf(w0, f0.y, a1);
            a2 = fmaf(w0, f1.x, a2); a3 = fmaf(w0, f1.y, a3);
            a4 = fmaf(w0, f2.x, a4); a5 = fmaf(w0, f2.y, a5);
            a6 = fmaf(w0, f3.x, a6); a7 = fmaf(w0, f3.y, a7);
        }
        {
            const __half2* hp = (const __half2*)&u1;
            float2 f0 = __half22float2(hp[0]);
            float2 f1 = __half22float2(hp[1]);
            float2 f2 = __half22float2(hp[2]);
            float2 f3 = __half22float2(hp[3]);
            a0 = fmaf(w1, f0.x, a0); a1 = fmaf(w1, f0.y, a1);
            a2 = fmaf(w1, f1.x, a2); a3 = fmaf(w1, f1.y, a3);
            a4 = fmaf(w1, f2.x, a4); a5 = fmaf(w1, f2.y, a5);
            a6 = fmaf(w1, f3.x, a6); a7 = fmaf(w1, f3.y, a7);
        }
    }
    if (j < m) {
        u64 p0 = pe[beg + j];
        unsigned s0 = (unsigned)p0;
        float    w0 = __uint_as_float((unsigned)(p0 >> 32));
        uint4 u0 = *(const uint4*)(xin + ((size_t)s0 << 6) + (c << 3));
        const __half2* hp = (const __half2*)&u0;
        float2 f0 = __half22float2(hp[0]);
        float2 f1 = __half22float2(hp[1]);
        float2 f2 = __half22float2(hp[2]);
        float2 f3 = __half22float2(hp[3]);
        a0 = fmaf(w0, f0.x, a0); a1 = fmaf(w0, f0.y, a1);
        a2 = fmaf(w0, f1.x, a2); a3 = fmaf(w0, f1.y, a3);
        a4 = fmaf(w0, f2.x, a4); a5 = fmaf(w0, f2.y, a5);
        a6 = fmaf(w0, f3.x, a6); a7 = fmaf(w0, f3.y, a7);
    }

    // self-loop
    float selfw = iso[node] * isi[node];
    {
        uint4 u = *(const uint4*)(xin + ((size_t)node << 6) + (c << 3));
        const __half2* hp = (const __half2*)&u;
        float2 f0 = __half22float2(hp[0]);
        float2 f1 = __half22float2(hp[1]);
        float2 f2 = __half22float2(hp[2]);
        float2 f3 = __half22float2(hp[3]);
        a0 = fmaf(selfw, f0.x, a0); a1 = fmaf(selfw, f0.y, a1);
        a2 = fmaf(selfw, f1.x, a2); a3 = fmaf(selfw, f1.y, a3);
        a4 = fmaf(selfw, f2.x, a4); a5 = fmaf(selfw, f2.y, a5);
        a6 = fmaf(selfw, f3.x, a6); a7 = fmaf(selfw, f3.y, a7);
    }

    // feat (fp32, stride 50): features 8*c .. 8*c+7, zero past 49
    float f[8] = {0.f, 0.f, 0.f, 0.f, 0.f, 0.f, 0.f, 0.f};
    int fb = c << 3;
    #pragma unroll
    for (int k = 0; k < 4; ++k) {
        int ff = fb + (k << 1);
        if (ff + 1 < D) {            // D even -> pairs fully valid or invalid
            float2 v = *(const float2*)(feat + (size_t)node * D + ff);
            f[k * 2] = v.x; f[k * 2 + 1] = v.y;
        }
    }

    float d0 = a0 - f[0], d1 = a1 - f[1], d2 = a2 - f[2], d3 = a3 - f[3];
    float d4 = a4 - f[4], d5 = a5 - f[5], d6 = a6 - f[6], d7 = a7 - f[7];

    float ssum = d0*d0 + d1*d1 + d2*d2 + d3*d3 + d4*d4 + d5*d5 + d6*d6 + d7*d7;
    ssum += __shfl_xor(ssum, 1, 64);     // stays within the 8-lane group
    ssum += __shfl_xor(ssum, 2, 64);
    ssum += __shfl_xor(ssum, 4, 64);
    float norm = sqrtf(ssum);
    float sc = (norm > 0.0f) ? fmaxf(norm - GLAM, 0.0f) / norm : 0.0f;

    float o0 = f[0] + sc * d0, o1 = f[1] + sc * d1;
    float o2 = f[2] + sc * d2, o3 = f[3] + sc * d3;
    float o4 = f[4] + sc * d4, o5 = f[5] + sc * d5;
    float o6 = f[6] + sc * d6, o7 = f[7] + sc * d7;
    if (!final_iter) {
        __half2 h0 = __float22half2_rn(make_float2(o0, o1));
        __half2 h1 = __float22half2_rn(make_float2(o2, o3));
        __half2 h2 = __float22half2_rn(make_float2(o4, o5));
        __half2 h3 = __float22half2_rn(make_float2(o6, o7));
        uint4 u;
        u.x = *(unsigned*)&h0; u.y = *(unsigned*)&h1;
        u.z = *(unsigned*)&h2; u.w = *(unsigned*)&h3;
        *(uint4*)(hout + ((size_t)node << 6) + (c << 3)) = u;
    } else {
        float o[8] = {o0, o1, o2, o3, o4, o5, o6, o7};
        #pragma unroll
        for (int k = 0; k < 4; ++k) {
            int ff = fb + (k << 1);
            if (ff + 1 < D) {
                float2 v; v.x = o[k * 2]; v.y = o[k * 2 + 1];
                *(float2*)(fout + (size_t)node * D + ff) = v;
            }
        }
    }
}

extern "C" void kernel_launch(void* const* d_in, const int* in_sizes, int n_in,
                              void* d_out, int out_size, void* d_ws, size_t ws_size,
                              hipStream_t stream) {
    const float* feat = (const float*)d_in[0];
    const float* ew   = (const float*)d_in[1];
    const int* src = (const int*)d_in[2];
    const int* dst = (const int*)d_in[3];

    const int nd = in_sizes[0];      // N * D
    const int n  = nd / D;           // N nodes
    const int e  = in_sizes[1];      // E edges
    const int np = n * PADH;         // padded fp16 element count

    const int nbuk = (n + BT - 1) / BT;         // 512-node buckets (196 @100k)
    const int nblk = (e + EPB - 1) / EPB;       // binning blocks (391 @1.6M)
    const int nm   = 2 * nbuk * nblk;           // count-matrix entries

    // workspace layout: 128B-aligned fp16 buffers first
    __half*   xpA    = (__half*)d_ws;           // np (fp16, rows 128B-aligned)
    __half*   xpB    = xpA + np;                // np
    u64*      bind   = (u64*)(xpB + np);        // e   (dst-binned records)
    u64*      pe     = bind + e;                // e   (final CSR: col|wv)
    unsigned* bins   = (unsigned*)(pe + e);     // e   (src-binned records)
    int*      mat    = (int*)(bins + e);        // nm
    int*      msc    = mat + nm;                // nm
    float*    isi    = (float*)(msc + nm);      // n
    float*    iso    = isi + n;                 // n
    int*      cnt    = (int*)(iso + n);         // n
    int*      rowptr = cnt + n;                 // n
    int*      bsum   = rowptr + n;              // 1024
    float*    out    = (float*)d_out;

    const int B = 256;
    const int gP  = (np + B - 1) / B;
    const int NBm = (nm + SCAN_B - 1) / SCAN_B;
    const int NBc = (n + SCAN_B - 1) / SCAN_B;

    k_b1<<<nblk, B, 0, stream>>>(src, dst, mat, e, nblk, nbuk);
    k_scan1<<<NBm, SCAN_B, 0, stream>>>(mat, msc, bsum, nm);
    k_scan2<<<1, SCAN_B, 0, stream>>>(bsum, NBm);
    k_scan3<<<NBm, SCAN_B, 0, stream>>>(msc, bsum, nm);
    k_b2<<<nblk, B, 0, stream>>>(ew, src, dst, msc, bind, bins, e, nblk, nbuk);
    k_hist2<<<2 * nbuk, BT, 0, stream>>>(bind, bins, msc, isi, iso, cnt, n, nblk, nbuk, e);
    k_scan1<<<NBc, SCAN_B, 0, stream>>>(cnt, rowptr, bsum, n);
    k_scan2<<<1, SCAN_B, 0, stream>>>(bsum, NBc);
    k_scan3<<<NBc, SCAN_B, 0, stream>>>(rowptr, bsum, n);
    k_fill<<<nbuk, BT, 0, stream>>>(bind, msc, rowptr, iso, isi, pe, n, nblk, nbuk, e);
    k_pad<<<gP, B, 0, stream>>>(feat, xpA, n);

    // 8 nodes per wave, 4 waves per block -> 32 nodes per block
    const int nodesPerBlock = (B / 64) * 8;
    const int iterGrid = (n + nodesPerBlock - 1) / nodesPerBlock;

    // iter1: xpA -> xpB ; iter2: xpB -> xpA ; iter3: xpA -> d_out (fp32)
    k_iter<<<iterGrid, B, 0, stream>>>(rowptr, cnt, pe, xpA, feat, iso, isi, xpB, out, n, 0);
    k_iter<<<iterGrid, B, 0, stream>>>(rowptr, cnt, pe, xpB, feat, iso, isi, xpA, out, n, 0);
    k_iter<<<iterGrid, B, 0, stream>>>(rowptr, cnt, pe, xpA, feat, iso, isi, xpA, out, n, 1);
}

// Round 14
// 282.968 us; speedup vs baseline: 1.7304x; 1.0511x over previous
//
#include <hip/hip_runtime.h>
#include <hip/hip_bf16.h>
#include <hip/hip_fp16.h>

#define D 50
#define PADH 64                     // fp16 row stride: 128 B = 2 aligned 64B lines
#define GLAM 0.05555555555555555f   // gamma * lambda = (1/(2*0.9)) * 0.1
#define SCAN_B 1024
#define FIXS 8388608.0f             // 2^23 fixed-point scale
#define INV_FIXS (1.0f / 8388608.0f)
#define EPB 8192                    // edges per binning block
#define B2T 512                     // threads for b1/b2
#define BSH 9                       // 512-node buckets
#define BMSK 511u
#define BT 512                      // threads for srcdeg/dstfill (= bucket size)
#define MAXB 256                    // max buckets (supports n <= 131072)

typedef unsigned long long u64;

// ---- pass 1: per-block LDS histograms over dst-bucket and src-bucket ----
__global__ void k_b1(const int* __restrict__ src, const int* __restrict__ dst,
                     int* __restrict__ mat, int e, int nblk, int nbuk) {
    __shared__ unsigned hd[MAXB], hs[MAXB];
    for (int j = threadIdx.x; j < nbuk; j += blockDim.x) { hd[j] = 0; hs[j] = 0; }
    __syncthreads();
    int base = blockIdx.x * EPB;
    int end = base + EPB; if (end > e) end = e;
    for (int i = base + threadIdx.x; i < end; i += blockDim.x) {
        int t = __builtin_nontemporal_load(dst + i);
        int s = __builtin_nontemporal_load(src + i);
        atomicAdd(&hd[t >> BSH], 1u);
        atomicAdd(&hs[s >> BSH], 1u);
    }
    __syncthreads();
    for (int j = threadIdx.x; j < nbuk; j += blockDim.x) {
        mat[j * nblk + blockIdx.x] = (int)hd[j];
        mat[(nbuk + j) * nblk + blockIdx.x] = (int)hs[j];
    }
}

// ---- 3-kernel exclusive scan ----
__global__ void k_scan1(const int* __restrict__ cnt, int* __restrict__ out,
                        int* __restrict__ bsum, int n) {
    __shared__ int s[SCAN_B];
    int i = blockIdx.x * SCAN_B + threadIdx.x;
    int v = (i < n) ? cnt[i] : 0;
    s[threadIdx.x] = v; __syncthreads();
    for (int off = 1; off < SCAN_B; off <<= 1) {
        int t = (threadIdx.x >= (unsigned)off) ? s[threadIdx.x - off] : 0;
        __syncthreads();
        s[threadIdx.x] += t; __syncthreads();
    }
    if (i < n) out[i] = s[threadIdx.x] - v;             // exclusive
    if (threadIdx.x == SCAN_B - 1) bsum[blockIdx.x] = s[threadIdx.x];
}

__global__ void k_scan2(int* __restrict__ bsum, int nb) {
    __shared__ int s[SCAN_B];
    int v = (threadIdx.x < (unsigned)nb) ? bsum[threadIdx.x] : 0;
    s[threadIdx.x] = v; __syncthreads();
    for (int off = 1; off < SCAN_B; off <<= 1) {
        int t = (threadIdx.x >= (unsigned)off) ? s[threadIdx.x - off] : 0;
        __syncthreads();
        s[threadIdx.x] += t; __syncthreads();
    }
    if (threadIdx.x < (unsigned)nb) bsum[threadIdx.x] = s[threadIdx.x] - v;  // exclusive
}

__global__ void k_scan3(int* __restrict__ out, const int* __restrict__ bsum, int n) {
    int i = blockIdx.x * SCAN_B + threadIdx.x;
    if (i < n) out[i] += bsum[blockIdx.x];
}

// ---- pass 2: reorder edges into dst-binned (u64) and src-binned (u32) ----
__global__ void k_b2(const float* __restrict__ ew, const int* __restrict__ src,
                     const int* __restrict__ dst, const int* __restrict__ msc,
                     u64* __restrict__ bind, unsigned* __restrict__ bins,
                     int e, int nblk, int nbuk) {
    __shared__ unsigned cd[MAXB], cs[MAXB];
    for (int j = threadIdx.x; j < nbuk; j += blockDim.x) {
        cd[j] = (unsigned)msc[j * nblk + blockIdx.x];
        cs[j] = (unsigned)msc[(nbuk + j) * nblk + blockIdx.x];
    }
    __syncthreads();
    int base = blockIdx.x * EPB;
    int end = base + EPB; if (end > e) end = e;
    for (int i = base + threadIdx.x; i < end; i += blockDim.x) {
        float w = __builtin_nontemporal_load(ew + i);
        int s = __builtin_nontemporal_load(src + i);
        int t = __builtin_nontemporal_load(dst + i);
        unsigned wfix = (unsigned)(w * FIXS + 0.5f);
        if (wfix > 0x7FFFFFu) wfix = 0x7FFFFFu;
        unsigned pd = atomicAdd(&cd[t >> BSH], 1u);
        bind[pd] = ((u64)__float_as_uint(w) << 32)
                 | ((unsigned)s << BSH) | (unsigned)(t & BMSK);
        unsigned ps = atomicAdd(&cs[s >> BSH], 1u);
        bins[ps - (unsigned)e] = (wfix << BSH) | (unsigned)(s & BMSK);
    }
}

// ---- src weighted degrees per bucket -> iso ----
__global__ void k_srcdeg(const unsigned* __restrict__ bins, const int* __restrict__ msc,
                         float* __restrict__ iso, int n, int nblk, int nbuk, int e) {
    __shared__ unsigned wl[BT];
    wl[threadIdx.x] = 0;
    __syncthreads();
    int b = blockIdx.x;
    int start = msc[(nbuk + b) * nblk] - e;
    int end = (b + 1 < nbuk) ? (msc[(nbuk + b + 1) * nblk] - e) : e;
    for (int i = start + threadIdx.x; i < end; i += blockDim.x) {
        unsigned r = bins[i];
        atomicAdd(&wl[r & BMSK], r >> BSH);
    }
    __syncthreads();
    int node = b * BT + threadIdx.x;
    if (node < n)
        iso[node] = rsqrtf(1.0f + (float)wl[threadIdx.x] * INV_FIXS);
}

// ---- merged: dst histogram + isi + local rowptr scan + CSR fill ----
__global__ void k_dstfill(const u64* __restrict__ bind, const int* __restrict__ msc,
                          const float* __restrict__ iso, float* __restrict__ isi,
                          int* __restrict__ cnt, int* __restrict__ rowptr,
                          u64* __restrict__ pe, int n, int nblk, int nbuk, int e) {
    __shared__ unsigned cl[BT], wl[BT], cur[BT];
    __shared__ int sc[BT];
    __shared__ float isL[BT];
    cl[threadIdx.x] = 0; wl[threadIdx.x] = 0;
    __syncthreads();
    int b = blockIdx.x;
    int start = msc[b * nblk];
    int end = (b + 1 < nbuk) ? msc[(b + 1) * nblk] : e;

    // pass A: histogram cnt + weighted degree
    for (int i = start + threadIdx.x; i < end; i += blockDim.x) {
        u64 r = bind[i];
        unsigned loc = (unsigned)r & BMSK;
        float w = __uint_as_float((unsigned)(r >> 32));
        unsigned wfix = (unsigned)(w * FIXS + 0.5f);
        if (wfix > 0x7FFFFFu) wfix = 0x7FFFFFu;
        atomicAdd(&cl[loc], 1u);
        atomicAdd(&wl[loc], wfix);
    }
    __syncthreads();

    // block-local exclusive scan of cl -> local rowptr
    int myc = (int)cl[threadIdx.x];
    sc[threadIdx.x] = myc;
    __syncthreads();
    for (int off = 1; off < BT; off <<= 1) {
        int t = (threadIdx.x >= (unsigned)off) ? sc[threadIdx.x - off] : 0;
        __syncthreads();
        sc[threadIdx.x] += t;
        __syncthreads();
    }
    int lrp = start + sc[threadIdx.x] - myc;

    float myisi = rsqrtf(1.0f + (float)wl[threadIdx.x] * INV_FIXS);
    isL[threadIdx.x] = myisi;
    cur[threadIdx.x] = (unsigned)lrp;

    int node = b * BT + threadIdx.x;
    if (node < n) {
        isi[node] = myisi;
        cnt[node] = myc;
        rowptr[node] = lrp;
    }
    __syncthreads();

    // pass B: fill CSR (bind run is L2-warm from pass A)
    for (int i = start + threadIdx.x; i < end; i += blockDim.x) {
        u64 r = bind[i];
        unsigned lo = (unsigned)r;
        unsigned tloc = lo & BMSK;
        unsigned s = lo >> BSH;
        float w = __uint_as_float((unsigned)(r >> 32));
        float wv = w * iso[s] * isL[tloc];
        unsigned pos = atomicAdd(&cur[tloc], 1u);
        pe[pos] = (u64)s | ((u64)__float_as_uint(wv) << 32);
    }
}

// ---- pad feat (stride 50 fp32) -> xp (stride 64 fp16, zeros in pad) ----
__global__ void k_pad(const float* __restrict__ feat, __half* __restrict__ xp, int n) {
    int i = blockIdx.x * blockDim.x + threadIdx.x;
    if (i < n * PADH) {
        int node = i >> 6, col = i & 63;
        xp[i] = (col < D) ? __float2half_rn(feat[node * D + col]) : __half(0.0f);
    }
}

// ---- fused iteration: 8 nodes per wave, 8 lanes per node, 16B gathers ----
__global__ void k_iter(const int* __restrict__ rowptr, const int* __restrict__ cnt,
                       const u64* __restrict__ pe, const __half* __restrict__ xin,
                       const float* __restrict__ feat, const float* __restrict__ iso,
                       const float* __restrict__ isi, __half* __restrict__ hout,
                       float* __restrict__ fout, int n, int final_iter) {
    int lane = threadIdx.x & 63;
    int c    = lane & 7;             // feature chunk 0..7 within group
    int waveId = (blockIdx.x * blockDim.x + threadIdx.x) >> 6;
    int node = waveId * 8 + (lane >> 3);
    if (node >= n) return;

    float a0 = 0.f, a1 = 0.f, a2 = 0.f, a3 = 0.f;
    float a4 = 0.f, a5 = 0.f, a6 = 0.f, a7 = 0.f;

    int beg = rowptr[node], m = cnt[node];

    int j = 0;
    for (; j + 2 <= m; j += 2) {
        u64 p0 = pe[beg + j];
        u64 p1 = pe[beg + j + 1];
        unsigned s0 = (unsigned)p0;
        float    w0 = __uint_as_float((unsigned)(p0 >> 32));
        unsigned s1 = (unsigned)p1;
        float    w1 = __uint_as_float((unsigned)(p1 >> 32));
        uint4 u0 = *(const uint4*)(xin + ((size_t)s0 << 6) + (c << 3));
        uint4 u1 = *(const uint4*)(xin + ((size_t)s1 << 6) + (c << 3));
        {
            const __half2* hp = (const __half2*)&u0;
            float2 f0 = __half22float2(hp[0]);
            float2 f1 = __half22float2(hp[1]);
            float2 f2 = __half22float2(hp[2]);
            float2 f3 = __half22float2(hp[3]);
            a0 = fmaf(w0, f0.x, a0); a1 = fmaf(w0, f0.y, a1);
            a2 = fmaf(w0, f1.x, a2); a3 = fmaf(w0, f1.y, a3);
            a4 = fmaf(w0, f2.x, a4); a5 = fmaf(w0, f2.y, a5);
            a6 = fmaf(w0, f3.x, a6); a7 = fmaf(w0, f3.y, a7);
        }
        {
            const __half2* hp = (const __half2*)&u1;
            float2 f0 = __half22float2(hp[0]);
            float2 f1 = __half22float2(hp[1]);
            float2 f2 = __half22float2(hp[2]);
            float2 f3 = __half22float2(hp[3]);
            a0 = fmaf(w1, f0.x, a0); a1 = fmaf(w1, f0.y, a1);
            a2 = fmaf(w1, f1.x, a2); a3 = fmaf(w1, f1.y, a3);
            a4 = fmaf(w1, f2.x, a4); a5 = fmaf(w1, f2.y, a5);
            a6 = fmaf(w1, f3.x, a6); a7 = fmaf(w1, f3.y, a7);
        }
    }
    if (j < m) {
        u64 p0 = pe[beg + j];
        unsigned s0 = (unsigned)p0;
        float    w0 = __uint_as_float((unsigned)(p0 >> 32));
        uint4 u0 = *(const uint4*)(xin + ((size_t)s0 << 6) + (c << 3));
        const __half2* hp = (const __half2*)&u0;
        float2 f0 = __half22float2(hp[0]);
        float2 f1 = __half22float2(hp[1]);
        float2 f2 = __half22float2(hp[2]);
        float2 f3 = __half22float2(hp[3]);
        a0 = fmaf(w0, f0.x, a0); a1 = fmaf(w0, f0.y, a1);
        a2 = fmaf(w0, f1.x, a2); a3 = fmaf(w0, f1.y, a3);
        a4 = fmaf(w0, f2.x, a4); a5 = fmaf(w0, f2.y, a5);
        a6 = fmaf(w0, f3.x, a6); a7 = fmaf(w0, f3.y, a7);
    }

    // self-loop
    float selfw = iso[node] * isi[node];
    {
        uint4 u = *(const uint4*)(xin + ((size_t)node << 6) + (c << 3));
        const __half2* hp = (const __half2*)&u;
        float2 f0 = __half22float2(hp[0]);
        float2 f1 = __half22float2(hp[1]);
        float2 f2 = __half22float2(hp[2]);
        float2 f3 = __half22float2(hp[3]);
        a0 = fmaf(selfw, f0.x, a0); a1 = fmaf(selfw, f0.y, a1);
        a2 = fmaf(selfw, f1.x, a2); a3 = fmaf(selfw, f1.y, a3);
        a4 = fmaf(selfw, f2.x, a4); a5 = fmaf(selfw, f2.y, a5);
        a6 = fmaf(selfw, f3.x, a6); a7 = fmaf(selfw, f3.y, a7);
    }

    // feat (fp32, stride 50): features 8*c .. 8*c+7, zero past 49
    float f[8] = {0.f, 0.f, 0.f, 0.f, 0.f, 0.f, 0.f, 0.f};
    int fb = c << 3;
    #pragma unroll
    for (int k = 0; k < 4; ++k) {
        int ff = fb + (k << 1);
        if (ff + 1 < D) {            // D even -> pairs fully valid or invalid
            float2 v = *(const float2*)(feat + (size_t)node * D + ff);
            f[k * 2] = v.x; f[k * 2 + 1] = v.y;
        }
    }

    float d0 = a0 - f[0], d1 = a1 - f[1], d2 = a2 - f[2], d3 = a3 - f[3];
    float d4 = a4 - f[4], d5 = a5 - f[5], d6 = a6 - f[6], d7 = a7 - f[7];

    float ssum = d0*d0 + d1*d1 + d2*d2 + d3*d3 + d4*d4 + d5*d5 + d6*d6 + d7*d7;
    ssum += __shfl_xor(ssum, 1, 64);     // stays within the 8-lane group
    ssum += __shfl_xor(ssum, 2, 64);
    ssum += __shfl_xor(ssum, 4, 64);
    float norm = sqrtf(ssum);
    float sc = (norm > 0.0f) ? fmaxf(norm - GLAM, 0.0f) / norm : 0.0f;

    float o0 = f[0] + sc * d0, o1 = f[1] + sc * d1;
    float o2 = f[2] + sc * d2, o3 = f[3] + sc * d3;
    float o4 = f[4] + sc * d4, o5 = f[5] + sc * d5;
    float o6 = f[6] + sc * d6, o7 = f[7] + sc * d7;
    if (!final_iter) {
        __half2 h0 = __float22half2_rn(make_float2(o0, o1));
        __half2 h1 = __float22half2_rn(make_float2(o2, o3));
        __half2 h2 = __float22half2_rn(make_float2(o4, o5));
        __half2 h3 = __float22half2_rn(make_float2(o6, o7));
        uint4 u;
        u.x = *(unsigned*)&h0; u.y = *(unsigned*)&h1;
        u.z = *(unsigned*)&h2; u.w = *(unsigned*)&h3;
        *(uint4*)(hout + ((size_t)node << 6) + (c << 3)) = u;
    } else {
        float o[8] = {o0, o1, o2, o3, o4, o5, o6, o7};
        #pragma unroll
        for (int k = 0; k < 4; ++k) {
            int ff = fb + (k << 1);
            if (ff + 1 < D) {
                float2 v; v.x = o[k * 2]; v.y = o[k * 2 + 1];
                *(float2*)(fout + (size_t)node * D + ff) = v;
            }
        }
    }
}

extern "C" void kernel_launch(void* const* d_in, const int* in_sizes, int n_in,
                              void* d_out, int out_size, void* d_ws, size_t ws_size,
                              hipStream_t stream) {
    const float* feat = (const float*)d_in[0];
    const float* ew   = (const float*)d_in[1];
    const int* src = (const int*)d_in[2];
    const int* dst = (const int*)d_in[3];

    const int nd = in_sizes[0];      // N * D
    const int n  = nd / D;           // N nodes
    const int e  = in_sizes[1];      // E edges
    const int np = n * PADH;         // padded fp16 element count

    const int nbuk = (n + BT - 1) / BT;         // 512-node buckets (196 @100k)
    const int nblk = (e + EPB - 1) / EPB;       // binning blocks (196 @1.6M)
    const int nm   = 2 * nbuk * nblk;           // count-matrix entries

    // workspace layout: 128B-aligned fp16 buffers first
    __half*   xpA    = (__half*)d_ws;           // np (fp16, rows 128B-aligned)
    __half*   xpB    = xpA + np;                // np
    u64*      bind   = (u64*)(xpB + np);        // e   (dst-binned records)
    u64*      pe     = bind + e;                // e   (final CSR: col|wv)
    unsigned* bins   = (unsigned*)(pe + e);     // e   (src-binned records)
    int*      mat    = (int*)(bins + e);        // nm
    int*      msc    = mat + nm;                // nm
    float*    isi    = (float*)(msc + nm);      // n
    float*    iso    = isi + n;                 // n
    int*      cnt    = (int*)(iso + n);         // n
    int*      rowptr = cnt + n;                 // n
    int*      bsum   = rowptr + n;              // 1024
    float*    out    = (float*)d_out;

    const int B = 256;
    const int gP  = (np + B - 1) / B;
    const int NBm = (nm + SCAN_B - 1) / SCAN_B;

    k_b1<<<nblk, B2T, 0, stream>>>(src, dst, mat, e, nblk, nbuk);
    k_scan1<<<NBm, SCAN_B, 0, stream>>>(mat, msc, bsum, nm);
    k_scan2<<<1, SCAN_B, 0, stream>>>(bsum, NBm);
    k_scan3<<<NBm, SCAN_B, 0, stream>>>(msc, bsum, nm);
    k_b2<<<nblk, B2T, 0, stream>>>(ew, src, dst, msc, bind, bins, e, nblk, nbuk);
    k_srcdeg<<<nbuk, BT, 0, stream>>>(bins, msc, iso, n, nblk, nbuk, e);
    k_dstfill<<<nbuk, BT, 0, stream>>>(bind, msc, iso, isi, cnt, rowptr, pe, n, nblk, nbuk, e);
    k_pad<<<gP, B, 0, stream>>>(feat, xpA, n);

    // 8 nodes per wave, 4 waves per block -> 32 nodes per block
    const int nodesPerBlock = (B / 64) * 8;
    const int iterGrid = (n + nodesPerBlock - 1) / nodesPerBlock;

    // iter1: xpA -> xpB ; iter2: xpB -> xpA ; iter3: xpA -> d_out (fp32)
    k_iter<<<iterGrid, B, 0, stream>>>(rowptr, cnt, pe, xpA, feat, iso, isi, xpB, out, n, 0);
    k_iter<<<iterGrid, B, 0, stream>>>(rowptr, cnt, pe, xpB, feat, iso, isi, xpA, out, n, 0);
    k_iter<<<iterGrid, B, 0, stream>>>(rowptr, cnt, pe, xpA, feat, iso, isi, xpA, out, n, 1);
}

// Round 15
// 271.908 us; speedup vs baseline: 1.8008x; 1.0407x over previous
//
#include <hip/hip_runtime.h>
#include <hip/hip_bf16.h>
#include <hip/hip_fp16.h>

#define D 50
#define PADH 64                     // fp16 row stride: 128 B = 2 aligned 64B lines
#define GLAM 0.05555555555555555f   // gamma * lambda = (1/(2*0.9)) * 0.1
#define SCAN_B 1024
#define FIXS 8388608.0f             // 2^23 fixed-point scale
#define INV_FIXS (1.0f / 8388608.0f)
#define EPB 8192                    // edges per binning block
#define B2T 512                     // threads for b1/b2
#define BSH 9                       // 512-node buckets
#define BMSK 511u
#define BT 512                      // threads for srcdeg/dstfill (= bucket size)
#define MAXB 256                    // max buckets (supports n <= 131072)

typedef unsigned long long u64;

// ---- pass 1: per-block bucket histograms, FUSED with feat->fp16 pad ----
__global__ void k_b1p(const int* __restrict__ src, const int* __restrict__ dst,
                      int* __restrict__ mat, const float* __restrict__ feat,
                      __half* __restrict__ xp, int e, int nblk, int nbuk, int n) {
    if ((int)blockIdx.x < nblk) {
        __shared__ unsigned hd[MAXB], hs[MAXB];
        for (int j = threadIdx.x; j < nbuk; j += blockDim.x) { hd[j] = 0; hs[j] = 0; }
        __syncthreads();
        int base = blockIdx.x * EPB;
        int end = base + EPB; if (end > e) end = e;
        for (int i = base + threadIdx.x; i < end; i += blockDim.x) {
            int t = __builtin_nontemporal_load(dst + i);
            int s = __builtin_nontemporal_load(src + i);
            atomicAdd(&hd[t >> BSH], 1u);
            atomicAdd(&hs[s >> BSH], 1u);
        }
        __syncthreads();
        for (int j = threadIdx.x; j < nbuk; j += blockDim.x) {
            mat[j * nblk + blockIdx.x] = (int)hd[j];
            mat[(nbuk + j) * nblk + blockIdx.x] = (int)hs[j];
        }
    } else {
        int i = ((int)blockIdx.x - nblk) * (int)blockDim.x + (int)threadIdx.x;
        if (i < n * PADH) {
            int node = i >> 6, col = i & 63;
            xp[i] = (col < D) ? __float2half_rn(feat[node * D + col]) : __half(0.0f);
        }
    }
}

// ---- 3-kernel exclusive scan (for the bucket-count matrix) ----
__global__ void k_scan1(const int* __restrict__ cnt, int* __restrict__ out,
                        int* __restrict__ bsum, int n) {
    __shared__ int s[SCAN_B];
    int i = blockIdx.x * SCAN_B + threadIdx.x;
    int v = (i < n) ? cnt[i] : 0;
    s[threadIdx.x] = v; __syncthreads();
    for (int off = 1; off < SCAN_B; off <<= 1) {
        int t = (threadIdx.x >= (unsigned)off) ? s[threadIdx.x - off] : 0;
        __syncthreads();
        s[threadIdx.x] += t; __syncthreads();
    }
    if (i < n) out[i] = s[threadIdx.x] - v;             // exclusive
    if (threadIdx.x == SCAN_B - 1) bsum[blockIdx.x] = s[threadIdx.x];
}

__global__ void k_scan2(int* __restrict__ bsum, int nb) {
    __shared__ int s[SCAN_B];
    int v = (threadIdx.x < (unsigned)nb) ? bsum[threadIdx.x] : 0;
    s[threadIdx.x] = v; __syncthreads();
    for (int off = 1; off < SCAN_B; off <<= 1) {
        int t = (threadIdx.x >= (unsigned)off) ? s[threadIdx.x - off] : 0;
        __syncthreads();
        s[threadIdx.x] += t; __syncthreads();
    }
    if (threadIdx.x < (unsigned)nb) bsum[threadIdx.x] = s[threadIdx.x] - v;  // exclusive
}

__global__ void k_scan3(int* __restrict__ out, const int* __restrict__ bsum, int n) {
    int i = blockIdx.x * SCAN_B + threadIdx.x;
    if (i < n) out[i] += bsum[blockIdx.x];
}

// ---- pass 2: LDS counting sort per block -> coalesced binned writes ----
__global__ void k_b2(const float* __restrict__ ew, const int* __restrict__ src,
                     const int* __restrict__ dst, const int* __restrict__ msc,
                     u64* __restrict__ bind, unsigned* __restrict__ bins,
                     int e, int nblk, int nbuk) {
    __shared__ unsigned cd[MAXB], cs[MAXB];      // counts -> cursors
    __shared__ unsigned ld[MAXB], ls[MAXB];      // local exclusive starts
    __shared__ int gbd[MAXB], gbs[MAXB];         // global bases per bucket
    __shared__ u64 sd[EPB];                      // 64 KB dst-records staging
    __shared__ unsigned ss[EPB];                 // 32 KB src-records staging
    __shared__ unsigned char bdd[EPB], bds[EPB]; // bucket id per staged slot
    int tid = threadIdx.x;
    for (int j = tid; j < MAXB; j += blockDim.x) { cd[j] = 0; cs[j] = 0; }
    __syncthreads();
    int base = blockIdx.x * EPB;
    int end = base + EPB; if (end > e) end = e;
    int m = end - base;

    // phase 1: count buckets
    for (int i = base + tid; i < end; i += blockDim.x) {
        atomicAdd(&cd[(unsigned)__builtin_nontemporal_load(dst + i) >> BSH], 1u);
        atomicAdd(&cs[(unsigned)__builtin_nontemporal_load(src + i) >> BSH], 1u);
    }
    __syncthreads();

    // phase 2: exclusive scan over MAXB entries (first 256 threads)
    unsigned vd = 0, vs = 0;
    if (tid < MAXB) { vd = cd[tid]; vs = cs[tid]; ld[tid] = vd; ls[tid] = vs; }
    __syncthreads();
    for (int off = 1; off < MAXB; off <<= 1) {
        unsigned td = 0, ts = 0;
        if (tid < MAXB && tid >= off) { td = ld[tid - off]; ts = ls[tid - off]; }
        __syncthreads();
        if (tid < MAXB) { ld[tid] += td; ls[tid] += ts; }
        __syncthreads();
    }
    if (tid < MAXB) {
        ld[tid] -= vd; ls[tid] -= vs;            // exclusive starts
        cd[tid] = ld[tid]; cs[tid] = ls[tid];    // cursors
        if (tid < nbuk) {
            gbd[tid] = msc[tid * nblk + blockIdx.x];
            gbs[tid] = msc[(nbuk + tid) * nblk + blockIdx.x] - e;
        }
    }
    __syncthreads();

    // phase 3: place records into LDS staging
    for (int i = base + tid; i < end; i += blockDim.x) {
        float w = __builtin_nontemporal_load(ew + i);
        int s = __builtin_nontemporal_load(src + i);
        int t = __builtin_nontemporal_load(dst + i);
        unsigned wfix = (unsigned)(w * FIXS + 0.5f);
        if (wfix > 0x7FFFFFu) wfix = 0x7FFFFFu;
        unsigned tb = (unsigned)t >> BSH, sb = (unsigned)s >> BSH;
        unsigned pd = atomicAdd(&cd[tb], 1u);
        sd[pd] = ((u64)__float_as_uint(w) << 32)
               | ((unsigned)s << BSH) | (unsigned)(t & BMSK);
        bdd[pd] = (unsigned char)tb;
        unsigned ps = atomicAdd(&cs[sb], 1u);
        ss[ps] = (wfix << BSH) | (unsigned)(s & BMSK);
        bds[ps] = (unsigned char)sb;
    }
    __syncthreads();

    // phase 4: linear copy-out (coalesced within bucket runs)
    for (int p = tid; p < m; p += blockDim.x) {
        unsigned jd = bdd[p];
        bind[gbd[jd] + (int)(p - ld[jd])] = sd[p];
        unsigned js = bds[p];
        bins[gbs[js] + (int)(p - ls[js])] = ss[p];
    }
}

// ---- src weighted degrees per bucket -> iso ----
__global__ void k_srcdeg(const unsigned* __restrict__ bins, const int* __restrict__ msc,
                         float* __restrict__ iso, int n, int nblk, int nbuk, int e) {
    __shared__ unsigned wl[BT];
    wl[threadIdx.x] = 0;
    __syncthreads();
    int b = blockIdx.x;
    int start = msc[(nbuk + b) * nblk] - e;
    int end = (b + 1 < nbuk) ? (msc[(nbuk + b + 1) * nblk] - e) : e;
    for (int i = start + threadIdx.x; i < end; i += blockDim.x) {
        unsigned r = bins[i];
        atomicAdd(&wl[r & BMSK], r >> BSH);
    }
    __syncthreads();
    int node = b * BT + threadIdx.x;
    if (node < n)
        iso[node] = rsqrtf(1.0f + (float)wl[threadIdx.x] * INV_FIXS);
}

// ---- merged: dst histogram + isi + local rowptr scan + CSR fill ----
__global__ void k_dstfill(const u64* __restrict__ bind, const int* __restrict__ msc,
                          const float* __restrict__ iso, float* __restrict__ isi,
                          int* __restrict__ cnt, int* __restrict__ rowptr,
                          u64* __restrict__ pe, int n, int nblk, int nbuk, int e) {
    __shared__ unsigned cl[BT], wl[BT], cur[BT];
    __shared__ int sc[BT];
    __shared__ float isL[BT];
    cl[threadIdx.x] = 0; wl[threadIdx.x] = 0;
    __syncthreads();
    int b = blockIdx.x;
    int start = msc[b * nblk];
    int end = (b + 1 < nbuk) ? msc[(b + 1) * nblk] : e;

    // pass A: histogram cnt + weighted degree
    for (int i = start + threadIdx.x; i < end; i += blockDim.x) {
        u64 r = bind[i];
        unsigned loc = (unsigned)r & BMSK;
        float w = __uint_as_float((unsigned)(r >> 32));
        unsigned wfix = (unsigned)(w * FIXS + 0.5f);
        if (wfix > 0x7FFFFFu) wfix = 0x7FFFFFu;
        atomicAdd(&cl[loc], 1u);
        atomicAdd(&wl[loc], wfix);
    }
    __syncthreads();

    // block-local exclusive scan of cl -> local rowptr
    int myc = (int)cl[threadIdx.x];
    sc[threadIdx.x] = myc;
    __syncthreads();
    for (int off = 1; off < BT; off <<= 1) {
        int t = (threadIdx.x >= (unsigned)off) ? sc[threadIdx.x - off] : 0;
        __syncthreads();
        sc[threadIdx.x] += t;
        __syncthreads();
    }
    int lrp = start + sc[threadIdx.x] - myc;

    float myisi = rsqrtf(1.0f + (float)wl[threadIdx.x] * INV_FIXS);
    isL[threadIdx.x] = myisi;
    cur[threadIdx.x] = (unsigned)lrp;

    int node = b * BT + threadIdx.x;
    if (node < n) {
        isi[node] = myisi;
        cnt[node] = myc;
        rowptr[node] = lrp;
    }
    __syncthreads();

    // pass B: fill CSR (bind run is L2-warm from pass A)
    for (int i = start + threadIdx.x; i < end; i += blockDim.x) {
        u64 r = bind[i];
        unsigned lo = (unsigned)r;
        unsigned tloc = lo & BMSK;
        unsigned s = lo >> BSH;
        float w = __uint_as_float((unsigned)(r >> 32));
        float wv = w * iso[s] * isL[tloc];
        unsigned pos = atomicAdd(&cur[tloc], 1u);
        pe[pos] = (u64)s | ((u64)__float_as_uint(wv) << 32);
    }
}

// ---- fused iteration: 8 nodes per wave, 8 lanes per node, 16B gathers ----
__global__ void k_iter(const int* __restrict__ rowptr, const int* __restrict__ cnt,
                       const u64* __restrict__ pe, const __half* __restrict__ xin,
                       const __half* __restrict__ xpF, const float* __restrict__ iso,
                       const float* __restrict__ isi, __half* __restrict__ hout,
                       float* __restrict__ fout, int n, int final_iter) {
    int lane = threadIdx.x & 63;
    int c    = lane & 7;             // feature chunk 0..7 within group
    int waveId = (blockIdx.x * blockDim.x + threadIdx.x) >> 6;
    int node = waveId * 8 + (lane >> 3);
    if (node >= n) return;

    float a0 = 0.f, a1 = 0.f, a2 = 0.f, a3 = 0.f;
    float a4 = 0.f, a5 = 0.f, a6 = 0.f, a7 = 0.f;

    int beg = rowptr[node], m = cnt[node];

    int j = 0;
    for (; j + 2 <= m; j += 2) {
        u64 p0 = pe[beg + j];
        u64 p1 = pe[beg + j + 1];
        unsigned s0 = (unsigned)p0;
        float    w0 = __uint_as_float((unsigned)(p0 >> 32));
        unsigned s1 = (unsigned)p1;
        float    w1 = __uint_as_float((unsigned)(p1 >> 32));
        uint4 u0 = *(const uint4*)(xin + ((size_t)s0 << 6) + (c << 3));
        uint4 u1 = *(const uint4*)(xin + ((size_t)s1 << 6) + (c << 3));
        {
            const __half2* hp = (const __half2*)&u0;
            float2 f0 = __half22float2(hp[0]);
            float2 f1 = __half22float2(hp[1]);
            float2 f2 = __half22float2(hp[2]);
            float2 f3 = __half22float2(hp[3]);
            a0 = fmaf(w0, f0.x, a0); a1 = fmaf(w0, f0.y, a1);
            a2 = fmaf(w0, f1.x, a2); a3 = fmaf(w0, f1.y, a3);
            a4 = fmaf(w0, f2.x, a4); a5 = fmaf(w0, f2.y, a5);
            a6 = fmaf(w0, f3.x, a6); a7 = fmaf(w0, f3.y, a7);
        }
        {
            const __half2* hp = (const __half2*)&u1;
            float2 f0 = __half22float2(hp[0]);
            float2 f1 = __half22float2(hp[1]);
            float2 f2 = __half22float2(hp[2]);
            float2 f3 = __half22float2(hp[3]);
            a0 = fmaf(w1, f0.x, a0); a1 = fmaf(w1, f0.y, a1);
            a2 = fmaf(w1, f1.x, a2); a3 = fmaf(w1, f1.y, a3);
            a4 = fmaf(w1, f2.x, a4); a5 = fmaf(w1, f2.y, a5);
            a6 = fmaf(w1, f3.x, a6); a7 = fmaf(w1, f3.y, a7);
        }
    }
    if (j < m) {
        u64 p0 = pe[beg + j];
        unsigned s0 = (unsigned)p0;
        float    w0 = __uint_as_float((unsigned)(p0 >> 32));
        uint4 u0 = *(const uint4*)(xin + ((size_t)s0 << 6) + (c << 3));
        const __half2* hp = (const __half2*)&u0;
        float2 f0 = __half22float2(hp[0]);
        float2 f1 = __half22float2(hp[1]);
        float2 f2 = __half22float2(hp[2]);
        float2 f3 = __half22float2(hp[3]);
        a0 = fmaf(w0, f0.x, a0); a1 = fmaf(w0, f0.y, a1);
        a2 = fmaf(w0, f1.x, a2); a3 = fmaf(w0, f1.y, a3);
        a4 = fmaf(w0, f2.x, a4); a5 = fmaf(w0, f2.y, a5);
        a6 = fmaf(w0, f3.x, a6); a7 = fmaf(w0, f3.y, a7);
    }

    // self-loop
    float selfw = iso[node] * isi[node];
    {
        uint4 u = *(const uint4*)(xin + ((size_t)node << 6) + (c << 3));
        const __half2* hp = (const __half2*)&u;
        float2 f0 = __half22float2(hp[0]);
        float2 f1 = __half22float2(hp[1]);
        float2 f2 = __half22float2(hp[2]);
        float2 f3 = __half22float2(hp[3]);
        a0 = fmaf(selfw, f0.x, a0); a1 = fmaf(selfw, f0.y, a1);
        a2 = fmaf(selfw, f1.x, a2); a3 = fmaf(selfw, f1.y, a3);
        a4 = fmaf(selfw, f2.x, a4); a5 = fmaf(selfw, f2.y, a5);
        a6 = fmaf(selfw, f3.x, a6); a7 = fmaf(selfw, f3.y, a7);
    }

    // feat from padded fp16 copy (pad cols are zero -> d=0 there)
    float f[8];
    {
        uint4 u = *(const uint4*)(xpF + ((size_t)node << 6) + (c << 3));
        const __half2* hp = (const __half2*)&u;
        float2 f0 = __half22float2(hp[0]);
        float2 f1 = __half22float2(hp[1]);
        float2 f2 = __half22float2(hp[2]);
        float2 f3 = __half22float2(hp[3]);
        f[0] = f0.x; f[1] = f0.y; f[2] = f1.x; f[3] = f1.y;
        f[4] = f2.x; f[5] = f2.y; f[6] = f3.x; f[7] = f3.y;
    }

    float d0 = a0 - f[0], d1 = a1 - f[1], d2 = a2 - f[2], d3 = a3 - f[3];
    float d4 = a4 - f[4], d5 = a5 - f[5], d6 = a6 - f[6], d7 = a7 - f[7];

    float ssum = d0*d0 + d1*d1 + d2*d2 + d3*d3 + d4*d4 + d5*d5 + d6*d6 + d7*d7;
    ssum += __shfl_xor(ssum, 1, 64);     // stays within the 8-lane group
    ssum += __shfl_xor(ssum, 2, 64);
    ssum += __shfl_xor(ssum, 4, 64);
    float norm = sqrtf(ssum);
    float sc = (norm > 0.0f) ? fmaxf(norm - GLAM, 0.0f) / norm : 0.0f;

    float o0 = f[0] + sc * d0, o1 = f[1] + sc * d1;
    float o2 = f[2] + sc * d2, o3 = f[3] + sc * d3;
    float o4 = f[4] + sc * d4, o5 = f[5] + sc * d5;
    float o6 = f[6] + sc * d6, o7 = f[7] + sc * d7;
    if (!final_iter) {
        __half2 h0 = __float22half2_rn(make_float2(o0, o1));
        __half2 h1 = __float22half2_rn(make_float2(o2, o3));
        __half2 h2 = __float22half2_rn(make_float2(o4, o5));
        __half2 h3 = __float22half2_rn(make_float2(o6, o7));
        uint4 u;
        u.x = *(unsigned*)&h0; u.y = *(unsigned*)&h1;
        u.z = *(unsigned*)&h2; u.w = *(unsigned*)&h3;
        *(uint4*)(hout + ((size_t)node << 6) + (c << 3)) = u;
    } else {
        float o[8] = {o0, o1, o2, o3, o4, o5, o6, o7};
        int fb = c << 3;
        #pragma unroll
        for (int k = 0; k < 4; ++k) {
            int ff = fb + (k << 1);
            if (ff + 1 < D) {
                float2 v; v.x = o[k * 2]; v.y = o[k * 2 + 1];
                *(float2*)(fout + (size_t)node * D + ff) = v;
            }
        }
    }
}

extern "C" void kernel_launch(void* const* d_in, const int* in_sizes, int n_in,
                              void* d_out, int out_size, void* d_ws, size_t ws_size,
                              hipStream_t stream) {
    const float* feat = (const float*)d_in[0];
    const float* ew   = (const float*)d_in[1];
    const int* src = (const int*)d_in[2];
    const int* dst = (const int*)d_in[3];

    const int nd = in_sizes[0];      // N * D
    const int n  = nd / D;           // N nodes
    const int e  = in_sizes[1];      // E edges
    const int np = n * PADH;         // padded fp16 element count

    const int nbuk = (n + BT - 1) / BT;         // 512-node buckets (196 @100k)
    const int nblk = (e + EPB - 1) / EPB;       // binning blocks (196 @1.6M)
    const int nm   = 2 * nbuk * nblk;           // count-matrix entries

    // workspace layout: 128B-aligned fp16 buffers first
    __half*   xpF    = (__half*)d_ws;           // np (fp16 feat, persistent)
    __half*   xpA    = xpF + np;                // np
    __half*   xpB    = xpA + np;                // np
    u64*      bind   = (u64*)(xpB + np);        // e   (dst-binned records)
    u64*      pe     = bind + e;                // e   (final CSR: col|wv)
    unsigned* bins   = (unsigned*)(pe + e);     // e   (src-binned records)
    int*      mat    = (int*)(bins + e);        // nm
    int*      msc    = mat + nm;                // nm
    float*    isi    = (float*)(msc + nm);      // n
    float*    iso    = isi + n;                 // n
    int*      cnt    = (int*)(iso + n);         // n
    int*      rowptr = cnt + n;                 // n
    int*      bsum   = rowptr + n;              // 1024
    float*    out    = (float*)d_out;

    const int B = 256;
    const int gP  = (np + B2T - 1) / B2T;       // pad blocks (fused into b1)
    const int NBm = (nm + SCAN_B - 1) / SCAN_B;

    k_b1p<<<nblk + gP, B2T, 0, stream>>>(src, dst, mat, feat, xpF, e, nblk, nbuk, n);
    k_scan1<<<NBm, SCAN_B, 0, stream>>>(mat, msc, bsum, nm);
    k_scan2<<<1, SCAN_B, 0, stream>>>(bsum, NBm);
    k_scan3<<<NBm, SCAN_B, 0, stream>>>(msc, bsum, nm);
    k_b2<<<nblk, B2T, 0, stream>>>(ew, src, dst, msc, bind, bins, e, nblk, nbuk);
    k_srcdeg<<<nbuk, BT, 0, stream>>>(bins, msc, iso, n, nblk, nbuk, e);
    k_dstfill<<<nbuk, BT, 0, stream>>>(bind, msc, iso, isi, cnt, rowptr, pe, n, nblk, nbuk, e);

    // 8 nodes per wave, 4 waves per block -> 32 nodes per block
    const int nodesPerBlock = (B / 64) * 8;
    const int iterGrid = (n + nodesPerBlock - 1) / nodesPerBlock;

    // iter1: xpF -> xpA ; iter2: xpA -> xpB ; iter3: xpB -> d_out (fp32)
    k_iter<<<iterGrid, B, 0, stream>>>(rowptr, cnt, pe, xpF, xpF, iso, isi, xpA, out, n, 0);
    k_iter<<<iterGrid, B, 0, stream>>>(rowptr, cnt, pe, xpA, xpF, iso, isi, xpB, out, n, 0);
    k_iter<<<iterGrid, B, 0, stream>>>(rowptr, cnt, pe, xpB, xpF, iso, isi, xpA, out, n, 1);
}

// Round 16
// 266.466 us; speedup vs baseline: 1.8376x; 1.0204x over previous
//
#include <hip/hip_runtime.h>
#include <hip/hip_bf16.h>
#include <hip/hip_fp16.h>

#define D 50
#define PADH 64                     // fp16 row stride: 128 B = 2 aligned 64B lines
#define GLAM 0.05555555555555555f   // gamma * lambda = (1/(2*0.9)) * 0.1
#define SCAN_B 1024
#define FIXS 8388608.0f             // 2^23 fixed-point scale
#define INV_FIXS (1.0f / 8388608.0f)
#define EPB 8192                    // edges per binning block
#define B2T 512                     // threads for b1/b2
#define BSH 9                       // 512-node buckets
#define BMSK 511u
#define BT 512                      // threads for srcdeg/dstfill (= bucket size)
#define MAXB 256                    // max buckets (supports n <= 131072)

typedef unsigned long long u64;

// ---- pass 1: per-block bucket histograms, FUSED with feat->fp16 pad ----
__global__ void k_b1p(const int* __restrict__ src, const int* __restrict__ dst,
                      int* __restrict__ mat, const float* __restrict__ feat,
                      __half* __restrict__ xp, int e, int nblk, int nbuk, int n) {
    if ((int)blockIdx.x < nblk) {
        __shared__ unsigned hd[MAXB], hs[MAXB];
        for (int j = threadIdx.x; j < nbuk; j += blockDim.x) { hd[j] = 0; hs[j] = 0; }
        __syncthreads();
        int base = blockIdx.x * EPB;
        int end = base + EPB; if (end > e) end = e;
        for (int i = base + threadIdx.x; i < end; i += blockDim.x) {
            int t = __builtin_nontemporal_load(dst + i);
            int s = __builtin_nontemporal_load(src + i);
            atomicAdd(&hd[t >> BSH], 1u);
            atomicAdd(&hs[s >> BSH], 1u);
        }
        __syncthreads();
        for (int j = threadIdx.x; j < nbuk; j += blockDim.x) {
            mat[j * nblk + blockIdx.x] = (int)hd[j];
            mat[(nbuk + j) * nblk + blockIdx.x] = (int)hs[j];
        }
    } else {
        int i = ((int)blockIdx.x - nblk) * (int)blockDim.x + (int)threadIdx.x;
        if (i < n * PADH) {
            int node = i >> 6, col = i & 63;
            xp[i] = (col < D) ? __float2half_rn(feat[node * D + col]) : __half(0.0f);
        }
    }
}

// ---- 3-kernel exclusive scan (for the bucket-count matrix) ----
__global__ void k_scan1(const int* __restrict__ cnt, int* __restrict__ out,
                        int* __restrict__ bsum, int n) {
    __shared__ int s[SCAN_B];
    int i = blockIdx.x * SCAN_B + threadIdx.x;
    int v = (i < n) ? cnt[i] : 0;
    s[threadIdx.x] = v; __syncthreads();
    for (int off = 1; off < SCAN_B; off <<= 1) {
        int t = (threadIdx.x >= (unsigned)off) ? s[threadIdx.x - off] : 0;
        __syncthreads();
        s[threadIdx.x] += t; __syncthreads();
    }
    if (i < n) out[i] = s[threadIdx.x] - v;             // exclusive
    if (threadIdx.x == SCAN_B - 1) bsum[blockIdx.x] = s[threadIdx.x];
}

__global__ void k_scan2(int* __restrict__ bsum, int nb) {
    __shared__ int s[SCAN_B];
    int v = (threadIdx.x < (unsigned)nb) ? bsum[threadIdx.x] : 0;
    s[threadIdx.x] = v; __syncthreads();
    for (int off = 1; off < SCAN_B; off <<= 1) {
        int t = (threadIdx.x >= (unsigned)off) ? s[threadIdx.x - off] : 0;
        __syncthreads();
        s[threadIdx.x] += t; __syncthreads();
    }
    if (threadIdx.x < (unsigned)nb) bsum[threadIdx.x] = s[threadIdx.x] - v;  // exclusive
}

__global__ void k_scan3(int* __restrict__ out, const int* __restrict__ bsum, int n) {
    int i = blockIdx.x * SCAN_B + threadIdx.x;
    if (i < n) out[i] += bsum[blockIdx.x];
}

// ---- pass 2: LDS counting sort per block -> coalesced binned writes ----
__global__ void k_b2(const float* __restrict__ ew, const int* __restrict__ src,
                     const int* __restrict__ dst, const int* __restrict__ msc,
                     u64* __restrict__ bind, unsigned* __restrict__ bins,
                     int e, int nblk, int nbuk) {
    __shared__ unsigned cd[MAXB], cs[MAXB];      // counts -> cursors
    __shared__ unsigned ld[MAXB], ls[MAXB];      // local exclusive starts
    __shared__ int gbd[MAXB], gbs[MAXB];         // global bases per bucket
    __shared__ u64 sd[EPB];                      // 64 KB dst-records staging
    __shared__ unsigned ss[EPB];                 // 32 KB src-records staging
    __shared__ unsigned char bdd[EPB], bds[EPB]; // bucket id per staged slot
    int tid = threadIdx.x;
    for (int j = tid; j < MAXB; j += blockDim.x) { cd[j] = 0; cs[j] = 0; }
    __syncthreads();
    int base = blockIdx.x * EPB;
    int end = base + EPB; if (end > e) end = e;
    int m = end - base;

    // phase 1: count buckets
    for (int i = base + tid; i < end; i += blockDim.x) {
        atomicAdd(&cd[(unsigned)__builtin_nontemporal_load(dst + i) >> BSH], 1u);
        atomicAdd(&cs[(unsigned)__builtin_nontemporal_load(src + i) >> BSH], 1u);
    }
    __syncthreads();

    // phase 2: exclusive scan over MAXB entries (first 256 threads)
    unsigned vd = 0, vs = 0;
    if (tid < MAXB) { vd = cd[tid]; vs = cs[tid]; ld[tid] = vd; ls[tid] = vs; }
    __syncthreads();
    for (int off = 1; off < MAXB; off <<= 1) {
        unsigned td = 0, ts = 0;
        if (tid < MAXB && tid >= off) { td = ld[tid - off]; ts = ls[tid - off]; }
        __syncthreads();
        if (tid < MAXB) { ld[tid] += td; ls[tid] += ts; }
        __syncthreads();
    }
    if (tid < MAXB) {
        ld[tid] -= vd; ls[tid] -= vs;            // exclusive starts
        cd[tid] = ld[tid]; cs[tid] = ls[tid];    // cursors
        if (tid < nbuk) {
            gbd[tid] = msc[tid * nblk + blockIdx.x];
            gbs[tid] = msc[(nbuk + tid) * nblk + blockIdx.x] - e;
        }
    }
    __syncthreads();

    // phase 3: place records into LDS staging
    for (int i = base + tid; i < end; i += blockDim.x) {
        float w = __builtin_nontemporal_load(ew + i);
        int s = __builtin_nontemporal_load(src + i);
        int t = __builtin_nontemporal_load(dst + i);
        unsigned wfix = (unsigned)(w * FIXS + 0.5f);
        if (wfix > 0x7FFFFFu) wfix = 0x7FFFFFu;
        unsigned tb = (unsigned)t >> BSH, sb = (unsigned)s >> BSH;
        unsigned pd = atomicAdd(&cd[tb], 1u);
        sd[pd] = ((u64)__float_as_uint(w) << 32)
               | ((unsigned)s << BSH) | (unsigned)(t & BMSK);
        bdd[pd] = (unsigned char)tb;
        unsigned ps = atomicAdd(&cs[sb], 1u);
        ss[ps] = (wfix << BSH) | (unsigned)(s & BMSK);
        bds[ps] = (unsigned char)sb;
    }
    __syncthreads();

    // phase 4: linear copy-out (coalesced within bucket runs)
    for (int p = tid; p < m; p += blockDim.x) {
        unsigned jd = bdd[p];
        bind[gbd[jd] + (int)(p - ld[jd])] = sd[p];
        unsigned js = bds[p];
        bins[gbs[js] + (int)(p - ls[js])] = ss[p];
    }
}

// ---- src weighted degrees per bucket -> iso ----
__global__ void k_srcdeg(const unsigned* __restrict__ bins, const int* __restrict__ msc,
                         float* __restrict__ iso, int n, int nblk, int nbuk, int e) {
    __shared__ unsigned wl[BT];
    wl[threadIdx.x] = 0;
    __syncthreads();
    int b = blockIdx.x;
    int start = msc[(nbuk + b) * nblk] - e;
    int end = (b + 1 < nbuk) ? (msc[(nbuk + b + 1) * nblk] - e) : e;
    for (int i = start + threadIdx.x; i < end; i += blockDim.x) {
        unsigned r = bins[i];
        atomicAdd(&wl[r & BMSK], r >> BSH);
    }
    __syncthreads();
    int node = b * BT + threadIdx.x;
    if (node < n)
        iso[node] = rsqrtf(1.0f + (float)wl[threadIdx.x] * INV_FIXS);
}

// ---- merged: dst histogram + isi + local rowptr scan + CSR fill ----
__global__ void k_dstfill(const u64* __restrict__ bind, const int* __restrict__ msc,
                          const float* __restrict__ iso, float* __restrict__ isi,
                          int* __restrict__ cnt, int* __restrict__ rowptr,
                          u64* __restrict__ pe, int n, int nblk, int nbuk, int e) {
    __shared__ unsigned cl[BT], wl[BT], cur[BT];
    __shared__ int sc[BT];
    __shared__ float isL[BT];
    cl[threadIdx.x] = 0; wl[threadIdx.x] = 0;
    __syncthreads();
    int b = blockIdx.x;
    int start = msc[b * nblk];
    int end = (b + 1 < nbuk) ? msc[(b + 1) * nblk] : e;

    // pass A: histogram cnt + weighted degree
    for (int i = start + threadIdx.x; i < end; i += blockDim.x) {
        u64 r = bind[i];
        unsigned loc = (unsigned)r & BMSK;
        float w = __uint_as_float((unsigned)(r >> 32));
        unsigned wfix = (unsigned)(w * FIXS + 0.5f);
        if (wfix > 0x7FFFFFu) wfix = 0x7FFFFFu;
        atomicAdd(&cl[loc], 1u);
        atomicAdd(&wl[loc], wfix);
    }
    __syncthreads();

    // block-local exclusive scan of cl -> local rowptr
    int myc = (int)cl[threadIdx.x];
    sc[threadIdx.x] = myc;
    __syncthreads();
    for (int off = 1; off < BT; off <<= 1) {
        int t = (threadIdx.x >= (unsigned)off) ? sc[threadIdx.x - off] : 0;
        __syncthreads();
        sc[threadIdx.x] += t;
        __syncthreads();
    }
    int lrp = start + sc[threadIdx.x] - myc;

    float myisi = rsqrtf(1.0f + (float)wl[threadIdx.x] * INV_FIXS);
    isL[threadIdx.x] = myisi;
    cur[threadIdx.x] = (unsigned)lrp;

    int node = b * BT + threadIdx.x;
    if (node < n) {
        isi[node] = myisi;
        cnt[node] = myc;
        rowptr[node] = lrp;
    }
    __syncthreads();

    // pass B: fill CSR (bind run is L2-warm from pass A)
    for (int i = start + threadIdx.x; i < end; i += blockDim.x) {
        u64 r = bind[i];
        unsigned lo = (unsigned)r;
        unsigned tloc = lo & BMSK;
        unsigned s = lo >> BSH;
        float w = __uint_as_float((unsigned)(r >> 32));
        float wv = w * iso[s] * isL[tloc];
        unsigned pos = atomicAdd(&cur[tloc], 1u);
        pe[pos] = (u64)s | ((u64)__float_as_uint(wv) << 32);
    }
}

// ---- one edge's FMA into the 8 accumulators ----
__device__ __forceinline__ void acc_edge(const uint4& u, float w,
                                         float& a0, float& a1, float& a2, float& a3,
                                         float& a4, float& a5, float& a6, float& a7) {
    const __half2* hp = (const __half2*)&u;
    float2 f0 = __half22float2(hp[0]);
    float2 f1 = __half22float2(hp[1]);
    float2 f2 = __half22float2(hp[2]);
    float2 f3 = __half22float2(hp[3]);
    a0 = fmaf(w, f0.x, a0); a1 = fmaf(w, f0.y, a1);
    a2 = fmaf(w, f1.x, a2); a3 = fmaf(w, f1.y, a3);
    a4 = fmaf(w, f2.x, a4); a5 = fmaf(w, f2.y, a5);
    a6 = fmaf(w, f3.x, a6); a7 = fmaf(w, f3.y, a7);
}

// ---- fused iteration: 8 nodes/wave, 8 lanes/node, 4-edge-deep pipeline ----
__global__ void k_iter(const int* __restrict__ rowptr, const int* __restrict__ cnt,
                       const u64* __restrict__ pe, const __half* __restrict__ xin,
                       const __half* __restrict__ xpF, const float* __restrict__ iso,
                       const float* __restrict__ isi, __half* __restrict__ hout,
                       float* __restrict__ fout, int n, int final_iter) {
    int lane = threadIdx.x & 63;
    int c    = lane & 7;             // feature chunk 0..7 within group
    int waveId = (blockIdx.x * blockDim.x + threadIdx.x) >> 6;
    int node = waveId * 8 + (lane >> 3);
    if (node >= n) return;

    float a0 = 0.f, a1 = 0.f, a2 = 0.f, a3 = 0.f;
    float a4 = 0.f, a5 = 0.f, a6 = 0.f, a7 = 0.f;

    int beg = rowptr[node], m = cnt[node];

    int j = 0;
    for (; j + 4 <= m; j += 4) {
        u64 p0 = pe[beg + j];
        u64 p1 = pe[beg + j + 1];
        u64 p2 = pe[beg + j + 2];
        u64 p3 = pe[beg + j + 3];
        unsigned s0 = (unsigned)p0; float w0 = __uint_as_float((unsigned)(p0 >> 32));
        unsigned s1 = (unsigned)p1; float w1 = __uint_as_float((unsigned)(p1 >> 32));
        unsigned s2 = (unsigned)p2; float w2 = __uint_as_float((unsigned)(p2 >> 32));
        unsigned s3 = (unsigned)p3; float w3 = __uint_as_float((unsigned)(p3 >> 32));
        uint4 u0 = *(const uint4*)(xin + ((size_t)s0 << 6) + (c << 3));
        uint4 u1 = *(const uint4*)(xin + ((size_t)s1 << 6) + (c << 3));
        uint4 u2 = *(const uint4*)(xin + ((size_t)s2 << 6) + (c << 3));
        uint4 u3 = *(const uint4*)(xin + ((size_t)s3 << 6) + (c << 3));
        acc_edge(u0, w0, a0, a1, a2, a3, a4, a5, a6, a7);
        acc_edge(u1, w1, a0, a1, a2, a3, a4, a5, a6, a7);
        acc_edge(u2, w2, a0, a1, a2, a3, a4, a5, a6, a7);
        acc_edge(u3, w3, a0, a1, a2, a3, a4, a5, a6, a7);
    }
    for (; j < m; ++j) {
        u64 p0 = pe[beg + j];
        unsigned s0 = (unsigned)p0;
        float    w0 = __uint_as_float((unsigned)(p0 >> 32));
        uint4 u0 = *(const uint4*)(xin + ((size_t)s0 << 6) + (c << 3));
        acc_edge(u0, w0, a0, a1, a2, a3, a4, a5, a6, a7);
    }

    // self-loop
    float selfw = iso[node] * isi[node];
    {
        uint4 u = *(const uint4*)(xin + ((size_t)node << 6) + (c << 3));
        acc_edge(u, selfw, a0, a1, a2, a3, a4, a5, a6, a7);
    }

    // feat from padded fp16 copy (pad cols are zero -> d=0 there)
    float f[8];
    {
        uint4 u = *(const uint4*)(xpF + ((size_t)node << 6) + (c << 3));
        const __half2* hp = (const __half2*)&u;
        float2 f0 = __half22float2(hp[0]);
        float2 f1 = __half22float2(hp[1]);
        float2 f2 = __half22float2(hp[2]);
        float2 f3 = __half22float2(hp[3]);
        f[0] = f0.x; f[1] = f0.y; f[2] = f1.x; f[3] = f1.y;
        f[4] = f2.x; f[5] = f2.y; f[6] = f3.x; f[7] = f3.y;
    }

    float d0 = a0 - f[0], d1 = a1 - f[1], d2 = a2 - f[2], d3 = a3 - f[3];
    float d4 = a4 - f[4], d5 = a5 - f[5], d6 = a6 - f[6], d7 = a7 - f[7];

    float ssum = d0*d0 + d1*d1 + d2*d2 + d3*d3 + d4*d4 + d5*d5 + d6*d6 + d7*d7;
    ssum += __shfl_xor(ssum, 1, 64);     // stays within the 8-lane group
    ssum += __shfl_xor(ssum, 2, 64);
    ssum += __shfl_xor(ssum, 4, 64);
    float norm = sqrtf(ssum);
    float sc = (norm > 0.0f) ? fmaxf(norm - GLAM, 0.0f) / norm : 0.0f;

    float o0 = f[0] + sc * d0, o1 = f[1] + sc * d1;
    float o2 = f[2] + sc * d2, o3 = f[3] + sc * d3;
    float o4 = f[4] + sc * d4, o5 = f[5] + sc * d5;
    float o6 = f[6] + sc * d6, o7 = f[7] + sc * d7;
    if (!final_iter) {
        __half2 h0 = __float22half2_rn(make_float2(o0, o1));
        __half2 h1 = __float22half2_rn(make_float2(o2, o3));
        __half2 h2 = __float22half2_rn(make_float2(o4, o5));
        __half2 h3 = __float22half2_rn(make_float2(o6, o7));
        uint4 u;
        u.x = *(unsigned*)&h0; u.y = *(unsigned*)&h1;
        u.z = *(unsigned*)&h2; u.w = *(unsigned*)&h3;
        *(uint4*)(hout + ((size_t)node << 6) + (c << 3)) = u;
    } else {
        float o[8] = {o0, o1, o2, o3, o4, o5, o6, o7};
        int fb = c << 3;
        #pragma unroll
        for (int k = 0; k < 4; ++k) {
            int ff = fb + (k << 1);
            if (ff + 1 < D) {
                float2 v; v.x = o[k * 2]; v.y = o[k * 2 + 1];
                *(float2*)(fout + (size_t)node * D + ff) = v;
            }
        }
    }
}

extern "C" void kernel_launch(void* const* d_in, const int* in_sizes, int n_in,
                              void* d_out, int out_size, void* d_ws, size_t ws_size,
                              hipStream_t stream) {
    const float* feat = (const float*)d_in[0];
    const float* ew   = (const float*)d_in[1];
    const int* src = (const int*)d_in[2];
    const int* dst = (const int*)d_in[3];

    const int nd = in_sizes[0];      // N * D
    const int n  = nd / D;           // N nodes
    const int e  = in_sizes[1];      // E edges
    const int np = n * PADH;         // padded fp16 element count

    const int nbuk = (n + BT - 1) / BT;         // 512-node buckets (196 @100k)
    const int nblk = (e + EPB - 1) / EPB;       // binning blocks (196 @1.6M)
    const int nm   = 2 * nbuk * nblk;           // count-matrix entries

    // workspace layout: 128B-aligned fp16 buffers first
    __half*   xpF    = (__half*)d_ws;           // np (fp16 feat, persistent)
    __half*   xpA    = xpF + np;                // np
    __half*   xpB    = xpA + np;                // np
    u64*      bind   = (u64*)(xpB + np);        // e   (dst-binned records)
    u64*      pe     = bind + e;                // e   (final CSR: col|wv)
    unsigned* bins   = (unsigned*)(pe + e);     // e   (src-binned records)
    int*      mat    = (int*)(bins + e);        // nm
    int*      msc    = mat + nm;                // nm
    float*    isi    = (float*)(msc + nm);      // n
    float*    iso    = isi + n;                 // n
    int*      cnt    = (int*)(iso + n);         // n
    int*      rowptr = cnt + n;                 // n
    int*      bsum   = rowptr + n;              // 1024
    float*    out    = (float*)d_out;

    const int B = 256;
    const int gP  = (np + B2T - 1) / B2T;       // pad blocks (fused into b1)
    const int NBm = (nm + SCAN_B - 1) / SCAN_B;

    k_b1p<<<nblk + gP, B2T, 0, stream>>>(src, dst, mat, feat, xpF, e, nblk, nbuk, n);
    k_scan1<<<NBm, SCAN_B, 0, stream>>>(mat, msc, bsum, nm);
    k_scan2<<<1, SCAN_B, 0, stream>>>(bsum, NBm);
    k_scan3<<<NBm, SCAN_B, 0, stream>>>(msc, bsum, nm);
    k_b2<<<nblk, B2T, 0, stream>>>(ew, src, dst, msc, bind, bins, e, nblk, nbuk);
    k_srcdeg<<<nbuk, BT, 0, stream>>>(bins, msc, iso, n, nblk, nbuk, e);
    k_dstfill<<<nbuk, BT, 0, stream>>>(bind, msc, iso, isi, cnt, rowptr, pe, n, nblk, nbuk, e);

    // 8 nodes per wave, 4 waves per block -> 32 nodes per block
    const int nodesPerBlock = (B / 64) * 8;
    const int iterGrid = (n + nodesPerBlock - 1) / nodesPerBlock;

    // iter1: xpF -> xpA ; iter2: xpA -> xpB ; iter3: xpB -> d_out (fp32)
    k_iter<<<iterGrid, B, 0, stream>>>(rowptr, cnt, pe, xpF, xpF, iso, isi, xpA, out, n, 0);
    k_iter<<<iterGrid, B, 0, stream>>>(rowptr, cnt, pe, xpA, xpF, iso, isi, xpB, out, n, 0);
    k_iter<<<iterGrid, B, 0, stream>>>(rowptr, cnt, pe, xpB, xpF, iso, isi, xpA, out, n, 1);
}

// Round 17
// 258.676 us; speedup vs baseline: 1.8929x; 1.0301x over previous
//
#include <hip/hip_runtime.h>
#include <hip/hip_bf16.h>
#include <hip/hip_fp16.h>

#define D 50
#define PADH 64                     // fp16 row stride: 128 B = 2 aligned 64B lines
#define GLAM 0.05555555555555555f   // gamma * lambda = (1/(2*0.9)) * 0.1
#define SCAN_B 1024
#define FIXS 8388608.0f             // 2^23 fixed-point scale (degree sums)
#define INV_FIXS (1.0f / 8388608.0f)
#define WSC 32768.0f                // 2^15 weight scale for u32 CSR records
#define INV_WSC (1.0f / 32768.0f)
#define EPB 8192                    // edges per binning block
#define B2T 512                     // threads for b1/b2
#define BSH 9                       // 512-node buckets
#define BMSK 511u
#define BT 512                      // threads for srcdeg/dstfill (= bucket size)
#define MAXB 256                    // max buckets (supports n <= 131072)
#define MAXRUN 12288                // LDS staging capacity in k_dstfill (96 KB)

typedef unsigned long long u64;

// ---- pass 1: per-block bucket histograms, FUSED with feat->fp16 pad ----
__global__ void k_b1p(const int* __restrict__ src, const int* __restrict__ dst,
                      int* __restrict__ mat, const float* __restrict__ feat,
                      __half* __restrict__ xp, int e, int nblk, int nbuk, int n) {
    if ((int)blockIdx.x < nblk) {
        __shared__ unsigned hd[MAXB], hs[MAXB];
        for (int j = threadIdx.x; j < nbuk; j += blockDim.x) { hd[j] = 0; hs[j] = 0; }
        __syncthreads();
        int base = blockIdx.x * EPB;
        int end = base + EPB; if (end > e) end = e;
        for (int i = base + threadIdx.x; i < end; i += blockDim.x) {
            int t = __builtin_nontemporal_load(dst + i);
            int s = __builtin_nontemporal_load(src + i);
            atomicAdd(&hd[t >> BSH], 1u);
            atomicAdd(&hs[s >> BSH], 1u);
        }
        __syncthreads();
        for (int j = threadIdx.x; j < nbuk; j += blockDim.x) {
            mat[j * nblk + blockIdx.x] = (int)hd[j];
            mat[(nbuk + j) * nblk + blockIdx.x] = (int)hs[j];
        }
    } else {
        int i = ((int)blockIdx.x - nblk) * (int)blockDim.x + (int)threadIdx.x;
        if (i < n * PADH) {
            int node = i >> 6, col = i & 63;
            xp[i] = (col < D) ? __float2half_rn(feat[node * D + col]) : __half(0.0f);
        }
    }
}

// ---- 3-kernel exclusive scan (for the bucket-count matrix) ----
__global__ void k_scan1(const int* __restrict__ cnt, int* __restrict__ out,
                        int* __restrict__ bsum, int n) {
    __shared__ int s[SCAN_B];
    int i = blockIdx.x * SCAN_B + threadIdx.x;
    int v = (i < n) ? cnt[i] : 0;
    s[threadIdx.x] = v; __syncthreads();
    for (int off = 1; off < SCAN_B; off <<= 1) {
        int t = (threadIdx.x >= (unsigned)off) ? s[threadIdx.x - off] : 0;
        __syncthreads();
        s[threadIdx.x] += t; __syncthreads();
    }
    if (i < n) out[i] = s[threadIdx.x] - v;             // exclusive
    if (threadIdx.x == SCAN_B - 1) bsum[blockIdx.x] = s[threadIdx.x];
}

__global__ void k_scan2(int* __restrict__ bsum, int nb) {
    __shared__ int s[SCAN_B];
    int v = (threadIdx.x < (unsigned)nb) ? bsum[threadIdx.x] : 0;
    s[threadIdx.x] = v; __syncthreads();
    for (int off = 1; off < SCAN_B; off <<= 1) {
        int t = (threadIdx.x >= (unsigned)off) ? s[threadIdx.x - off] : 0;
        __syncthreads();
        s[threadIdx.x] += t; __syncthreads();
    }
    if (threadIdx.x < (unsigned)nb) bsum[threadIdx.x] = s[threadIdx.x] - v;  // exclusive
}

__global__ void k_scan3(int* __restrict__ out, const int* __restrict__ bsum, int n) {
    int i = blockIdx.x * SCAN_B + threadIdx.x;
    if (i < n) out[i] += bsum[blockIdx.x];
}

// ---- pass 2: LDS counting sort per block -> coalesced binned writes ----
__global__ void k_b2(const float* __restrict__ ew, const int* __restrict__ src,
                     const int* __restrict__ dst, const int* __restrict__ msc,
                     u64* __restrict__ bind, unsigned* __restrict__ bins,
                     int e, int nblk, int nbuk) {
    __shared__ unsigned cd[MAXB], cs[MAXB];      // counts -> cursors
    __shared__ unsigned ld[MAXB], ls[MAXB];      // local exclusive starts
    __shared__ int gbd[MAXB], gbs[MAXB];         // global bases per bucket
    __shared__ u64 sd[EPB];                      // 64 KB dst-records staging
    __shared__ unsigned ss[EPB];                 // 32 KB src-records staging
    __shared__ unsigned char bdd[EPB], bds[EPB]; // bucket id per staged slot
    int tid = threadIdx.x;
    for (int j = tid; j < MAXB; j += blockDim.x) { cd[j] = 0; cs[j] = 0; }
    __syncthreads();
    int base = blockIdx.x * EPB;
    int end = base + EPB; if (end > e) end = e;
    int m = end - base;

    // phase 1: count buckets
    for (int i = base + tid; i < end; i += blockDim.x) {
        atomicAdd(&cd[(unsigned)__builtin_nontemporal_load(dst + i) >> BSH], 1u);
        atomicAdd(&cs[(unsigned)__builtin_nontemporal_load(src + i) >> BSH], 1u);
    }
    __syncthreads();

    // phase 2: exclusive scan over MAXB entries (first 256 threads)
    unsigned vd = 0, vs = 0;
    if (tid < MAXB) { vd = cd[tid]; vs = cs[tid]; ld[tid] = vd; ls[tid] = vs; }
    __syncthreads();
    for (int off = 1; off < MAXB; off <<= 1) {
        unsigned td = 0, ts = 0;
        if (tid < MAXB && tid >= off) { td = ld[tid - off]; ts = ls[tid - off]; }
        __syncthreads();
        if (tid < MAXB) { ld[tid] += td; ls[tid] += ts; }
        __syncthreads();
    }
    if (tid < MAXB) {
        ld[tid] -= vd; ls[tid] -= vs;            // exclusive starts
        cd[tid] = ld[tid]; cs[tid] = ls[tid];    // cursors
        if (tid < nbuk) {
            gbd[tid] = msc[tid * nblk + blockIdx.x];
            gbs[tid] = msc[(nbuk + tid) * nblk + blockIdx.x] - e;
        }
    }
    __syncthreads();

    // phase 3: place records into LDS staging
    for (int i = base + tid; i < end; i += blockDim.x) {
        float w = __builtin_nontemporal_load(ew + i);
        int s = __builtin_nontemporal_load(src + i);
        int t = __builtin_nontemporal_load(dst + i);
        unsigned wfix = (unsigned)(w * FIXS + 0.5f);
        if (wfix > 0x7FFFFFu) wfix = 0x7FFFFFu;
        unsigned tb = (unsigned)t >> BSH, sb = (unsigned)s >> BSH;
        unsigned pd = atomicAdd(&cd[tb], 1u);
        sd[pd] = ((u64)__float_as_uint(w) << 32)
               | ((unsigned)s << BSH) | (unsigned)(t & BMSK);
        bdd[pd] = (unsigned char)tb;
        unsigned ps = atomicAdd(&cs[sb], 1u);
        ss[ps] = (wfix << BSH) | (unsigned)(s & BMSK);
        bds[ps] = (unsigned char)sb;
    }
    __syncthreads();

    // phase 4: linear copy-out (coalesced within bucket runs)
    for (int p = tid; p < m; p += blockDim.x) {
        unsigned jd = bdd[p];
        bind[gbd[jd] + (int)(p - ld[jd])] = sd[p];
        unsigned js = bds[p];
        bins[gbs[js] + (int)(p - ls[js])] = ss[p];
    }
}

// ---- src weighted degrees per bucket -> iso ----
__global__ void k_srcdeg(const unsigned* __restrict__ bins, const int* __restrict__ msc,
                         float* __restrict__ iso, int n, int nblk, int nbuk, int e) {
    __shared__ unsigned wl[BT];
    wl[threadIdx.x] = 0;
    __syncthreads();
    int b = blockIdx.x;
    int start = msc[(nbuk + b) * nblk] - e;
    int end = (b + 1 < nbuk) ? (msc[(nbuk + b + 1) * nblk] - e) : e;
    for (int i = start + threadIdx.x; i < end; i += blockDim.x) {
        unsigned r = bins[i];
        atomicAdd(&wl[r & BMSK], r >> BSH);
    }
    __syncthreads();
    int node = b * BT + threadIdx.x;
    if (node < n)
        iso[node] = rsqrtf(1.0f + (float)wl[threadIdx.x] * INV_FIXS);
}

// ---- merged: dst histogram + isi + local rowptr scan + CSR fill (u32 recs) ----
__global__ void k_dstfill(const u64* __restrict__ bind, const int* __restrict__ msc,
                          const float* __restrict__ iso, float* __restrict__ isi,
                          int* __restrict__ cnt, int* __restrict__ rowptr,
                          unsigned* __restrict__ pe, int n, int nblk, int nbuk, int e) {
    __shared__ u64 recs[MAXRUN];                 // 96 KB staging
    __shared__ unsigned cl[BT], wl[BT], cur[BT];
    __shared__ int sc[BT];
    __shared__ float isL[BT];
    cl[threadIdx.x] = 0; wl[threadIdx.x] = 0;
    __syncthreads();
    int b = blockIdx.x;
    int start = msc[b * nblk];
    int end = (b + 1 < nbuk) ? msc[(b + 1) * nblk] : e;
    int run = end - start;
    bool fast = (run <= MAXRUN);

    // pass A: load run (to LDS if it fits) + histogram cnt + weighted degree
    if (fast) {
        for (int i = threadIdx.x; i < run; i += blockDim.x) {
            u64 r = bind[start + i];
            recs[i] = r;
            unsigned loc = (unsigned)r & BMSK;
            float w = __uint_as_float((unsigned)(r >> 32));
            unsigned wfix = (unsigned)(w * FIXS + 0.5f);
            if (wfix > 0x7FFFFFu) wfix = 0x7FFFFFu;
            atomicAdd(&cl[loc], 1u);
            atomicAdd(&wl[loc], wfix);
        }
    } else {
        for (int i = start + threadIdx.x; i < end; i += blockDim.x) {
            u64 r = bind[i];
            unsigned loc = (unsigned)r & BMSK;
            float w = __uint_as_float((unsigned)(r >> 32));
            unsigned wfix = (unsigned)(w * FIXS + 0.5f);
            if (wfix > 0x7FFFFFu) wfix = 0x7FFFFFu;
            atomicAdd(&cl[loc], 1u);
            atomicAdd(&wl[loc], wfix);
        }
    }
    __syncthreads();

    // block-local exclusive scan of cl -> local rowptr
    int myc = (int)cl[threadIdx.x];
    sc[threadIdx.x] = myc;
    __syncthreads();
    for (int off = 1; off < BT; off <<= 1) {
        int t = (threadIdx.x >= (unsigned)off) ? sc[threadIdx.x - off] : 0;
        __syncthreads();
        sc[threadIdx.x] += t;
        __syncthreads();
    }
    int lrp = start + sc[threadIdx.x] - myc;

    float myisi = rsqrtf(1.0f + (float)wl[threadIdx.x] * INV_FIXS);
    isL[threadIdx.x] = myisi;
    cur[threadIdx.x] = (unsigned)lrp;

    int node = b * BT + threadIdx.x;
    if (node < n) {
        isi[node] = myisi;
        cnt[node] = myc;
        rowptr[node] = lrp;
    }
    __syncthreads();

    // pass B: fill CSR as u32 records (s<<15 | w*2^15)
    if (fast) {
        for (int i = threadIdx.x; i < run; i += blockDim.x) {
            u64 r = recs[i];
            unsigned lo = (unsigned)r;
            unsigned tloc = lo & BMSK;
            unsigned s = lo >> BSH;
            float w = __uint_as_float((unsigned)(r >> 32));
            float wv = w * iso[s] * isL[tloc];
            unsigned wq = (unsigned)(wv * WSC + 0.5f);
            if (wq > 32767u) wq = 32767u;
            unsigned pos = atomicAdd(&cur[tloc], 1u);
            pe[pos] = (s << 15) | wq;
        }
    } else {
        for (int i = start + threadIdx.x; i < end; i += blockDim.x) {
            u64 r = bind[i];
            unsigned lo = (unsigned)r;
            unsigned tloc = lo & BMSK;
            unsigned s = lo >> BSH;
            float w = __uint_as_float((unsigned)(r >> 32));
            float wv = w * iso[s] * isL[tloc];
            unsigned wq = (unsigned)(wv * WSC + 0.5f);
            if (wq > 32767u) wq = 32767u;
            unsigned pos = atomicAdd(&cur[tloc], 1u);
            pe[pos] = (s << 15) | wq;
        }
    }
}

// ---- one edge's FMA into the 8 accumulators ----
__device__ __forceinline__ void acc_edge(const uint4& u, float w,
                                         float& a0, float& a1, float& a2, float& a3,
                                         float& a4, float& a5, float& a6, float& a7) {
    const __half2* hp = (const __half2*)&u;
    float2 f0 = __half22float2(hp[0]);
    float2 f1 = __half22float2(hp[1]);
    float2 f2 = __half22float2(hp[2]);
    float2 f3 = __half22float2(hp[3]);
    a0 = fmaf(w, f0.x, a0); a1 = fmaf(w, f0.y, a1);
    a2 = fmaf(w, f1.x, a2); a3 = fmaf(w, f1.y, a3);
    a4 = fmaf(w, f2.x, a4); a5 = fmaf(w, f2.y, a5);
    a6 = fmaf(w, f3.x, a6); a7 = fmaf(w, f3.y, a7);
}

// ---- fused iteration: 8 nodes/wave, 8 lanes/node, 4-edge-deep pipeline ----
__global__ void k_iter(const int* __restrict__ rowptr, const int* __restrict__ cnt,
                       const unsigned* __restrict__ pe, const __half* __restrict__ xin,
                       const __half* __restrict__ xpF, const float* __restrict__ iso,
                       const float* __restrict__ isi, __half* __restrict__ hout,
                       float* __restrict__ fout, int n, int final_iter) {
    int lane = threadIdx.x & 63;
    int c    = lane & 7;             // feature chunk 0..7 within group
    int waveId = (blockIdx.x * blockDim.x + threadIdx.x) >> 6;
    int node = waveId * 8 + (lane >> 3);
    if (node >= n) return;

    float a0 = 0.f, a1 = 0.f, a2 = 0.f, a3 = 0.f;
    float a4 = 0.f, a5 = 0.f, a6 = 0.f, a7 = 0.f;

    int beg = rowptr[node], m = cnt[node];

    int j = 0;
    for (; j + 4 <= m; j += 4) {
        unsigned p0 = pe[beg + j];
        unsigned p1 = pe[beg + j + 1];
        unsigned p2 = pe[beg + j + 2];
        unsigned p3 = pe[beg + j + 3];
        unsigned s0 = p0 >> 15; float w0 = (float)(p0 & 32767u) * INV_WSC;
        unsigned s1 = p1 >> 15; float w1 = (float)(p1 & 32767u) * INV_WSC;
        unsigned s2 = p2 >> 15; float w2 = (float)(p2 & 32767u) * INV_WSC;
        unsigned s3 = p3 >> 15; float w3 = (float)(p3 & 32767u) * INV_WSC;
        uint4 u0 = *(const uint4*)(xin + ((size_t)s0 << 6) + (c << 3));
        uint4 u1 = *(const uint4*)(xin + ((size_t)s1 << 6) + (c << 3));
        uint4 u2 = *(const uint4*)(xin + ((size_t)s2 << 6) + (c << 3));
        uint4 u3 = *(const uint4*)(xin + ((size_t)s3 << 6) + (c << 3));
        acc_edge(u0, w0, a0, a1, a2, a3, a4, a5, a6, a7);
        acc_edge(u1, w1, a0, a1, a2, a3, a4, a5, a6, a7);
        acc_edge(u2, w2, a0, a1, a2, a3, a4, a5, a6, a7);
        acc_edge(u3, w3, a0, a1, a2, a3, a4, a5, a6, a7);
    }
    for (; j < m; ++j) {
        unsigned p0 = pe[beg + j];
        unsigned s0 = p0 >> 15;
        float    w0 = (float)(p0 & 32767u) * INV_WSC;
        uint4 u0 = *(const uint4*)(xin + ((size_t)s0 << 6) + (c << 3));
        acc_edge(u0, w0, a0, a1, a2, a3, a4, a5, a6, a7);
    }

    // self-loop
    float selfw = iso[node] * isi[node];
    {
        uint4 u = *(const uint4*)(xin + ((size_t)node << 6) + (c << 3));
        acc_edge(u, selfw, a0, a1, a2, a3, a4, a5, a6, a7);
    }

    // feat from padded fp16 copy (pad cols are zero -> d=0 there)
    float f[8];
    {
        uint4 u = *(const uint4*)(xpF + ((size_t)node << 6) + (c << 3));
        const __half2* hp = (const __half2*)&u;
        float2 f0 = __half22float2(hp[0]);
        float2 f1 = __half22float2(hp[1]);
        float2 f2 = __half22float2(hp[2]);
        float2 f3 = __half22float2(hp[3]);
        f[0] = f0.x; f[1] = f0.y; f[2] = f1.x; f[3] = f1.y;
        f[4] = f2.x; f[5] = f2.y; f[6] = f3.x; f[7] = f3.y;
    }

    float d0 = a0 - f[0], d1 = a1 - f[1], d2 = a2 - f[2], d3 = a3 - f[3];
    float d4 = a4 - f[4], d5 = a5 - f[5], d6 = a6 - f[6], d7 = a7 - f[7];

    float ssum = d0*d0 + d1*d1 + d2*d2 + d3*d3 + d4*d4 + d5*d5 + d6*d6 + d7*d7;
    ssum += __shfl_xor(ssum, 1, 64);     // stays within the 8-lane group
    ssum += __shfl_xor(ssum, 2, 64);
    ssum += __shfl_xor(ssum, 4, 64);
    float norm = sqrtf(ssum);
    float sc = (norm > 0.0f) ? fmaxf(norm - GLAM, 0.0f) / norm : 0.0f;

    float o0 = f[0] + sc * d0, o1 = f[1] + sc * d1;
    float o2 = f[2] + sc * d2, o3 = f[3] + sc * d3;
    float o4 = f[4] + sc * d4, o5 = f[5] + sc * d5;
    float o6 = f[6] + sc * d6, o7 = f[7] + sc * d7;
    if (!final_iter) {
        __half2 h0 = __float22half2_rn(make_float2(o0, o1));
        __half2 h1 = __float22half2_rn(make_float2(o2, o3));
        __half2 h2 = __float22half2_rn(make_float2(o4, o5));
        __half2 h3 = __float22half2_rn(make_float2(o6, o7));
        uint4 u;
        u.x = *(unsigned*)&h0; u.y = *(unsigned*)&h1;
        u.z = *(unsigned*)&h2; u.w = *(unsigned*)&h3;
        *(uint4*)(hout + ((size_t)node << 6) + (c << 3)) = u;
    } else {
        float o[8] = {o0, o1, o2, o3, o4, o5, o6, o7};
        int fb = c << 3;
        #pragma unroll
        for (int k = 0; k < 4; ++k) {
            int ff = fb + (k << 1);
            if (ff + 1 < D) {
                float2 v; v.x = o[k * 2]; v.y = o[k * 2 + 1];
                *(float2*)(fout + (size_t)node * D + ff) = v;
            }
        }
    }
}

extern "C" void kernel_launch(void* const* d_in, const int* in_sizes, int n_in,
                              void* d_out, int out_size, void* d_ws, size_t ws_size,
                              hipStream_t stream) {
    const float* feat = (const float*)d_in[0];
    const float* ew   = (const float*)d_in[1];
    const int* src = (const int*)d_in[2];
    const int* dst = (const int*)d_in[3];

    const int nd = in_sizes[0];      // N * D
    const int n  = nd / D;           // N nodes
    const int e  = in_sizes[1];      // E edges
    const int np = n * PADH;         // padded fp16 element count

    const int nbuk = (n + BT - 1) / BT;         // 512-node buckets (196 @100k)
    const int nblk = (e + EPB - 1) / EPB;       // binning blocks (196 @1.6M)
    const int nm   = 2 * nbuk * nblk;           // count-matrix entries

    // workspace layout: 128B-aligned fp16 buffers first
    __half*   xpF    = (__half*)d_ws;           // np (fp16 feat, persistent)
    __half*   xpA    = xpF + np;                // np
    __half*   xpB    = xpA + np;                // np
    u64*      bind   = (u64*)(xpB + np);        // e   (dst-binned records)
    unsigned* pe     = (unsigned*)(bind + e);   // e   (final CSR: u32 s|w)
    unsigned* bins   = pe + e;                  // e   (src-binned records)
    int*      mat    = (int*)(bins + e);        // nm
    int*      msc    = mat + nm;                // nm
    float*    isi    = (float*)(msc + nm);      // n
    float*    iso    = isi + n;                 // n
    int*      cnt    = (int*)(iso + n);         // n
    int*      rowptr = cnt + n;                 // n
    int*      bsum   = rowptr + n;              // 1024
    float*    out    = (float*)d_out;

    const int B = 256;
    const int gP  = (np + B2T - 1) / B2T;       // pad blocks (fused into b1)
    const int NBm = (nm + SCAN_B - 1) / SCAN_B;

    k_b1p<<<nblk + gP, B2T, 0, stream>>>(src, dst, mat, feat, xpF, e, nblk, nbuk, n);
    k_scan1<<<NBm, SCAN_B, 0, stream>>>(mat, msc, bsum, nm);
    k_scan2<<<1, SCAN_B, 0, stream>>>(bsum, NBm);
    k_scan3<<<NBm, SCAN_B, 0, stream>>>(msc, bsum, nm);
    k_b2<<<nblk, B2T, 0, stream>>>(ew, src, dst, msc, bind, bins, e, nblk, nbuk);
    k_srcdeg<<<nbuk, BT, 0, stream>>>(bins, msc, iso, n, nblk, nbuk, e);
    k_dstfill<<<nbuk, BT, 0, stream>>>(bind, msc, iso, isi, cnt, rowptr, pe, n, nblk, nbuk, e);

    // 8 nodes per wave, 4 waves per block -> 32 nodes per block
    const int nodesPerBlock = (B / 64) * 8;
    const int iterGrid = (n + nodesPerBlock - 1) / nodesPerBlock;

    // iter1: xpF -> xpA ; iter2: xpA -> xpB ; iter3: xpB -> d_out (fp32)
    k_iter<<<iterGrid, B, 0, stream>>>(rowptr, cnt, pe, xpF, xpF, iso, isi, xpA, out, n, 0);
    k_iter<<<iterGrid, B, 0, stream>>>(rowptr, cnt, pe, xpA, xpF, iso, isi, xpB, out, n, 0);
    k_iter<<<iterGrid, B, 0, stream>>>(rowptr, cnt, pe, xpB, xpF, iso, isi, xpA, out, n, 1);
}